// Round 13
// baseline (1041.795 us; speedup 1.0000x reference)
//
#include <hip/hip_runtime.h>
#include <hip/hip_bf16.h>
#include <stdint.h>

#define B_ 32
#define T_ 128
#define H_ 1024
#define V_ 32000
#define NBLK_REC 64

typedef unsigned short u16;
typedef __attribute__((ext_vector_type(8))) short short8;
typedef __attribute__((ext_vector_type(4))) float f32x4;
typedef __attribute__((ext_vector_type(4))) unsigned u32x4;

static __device__ __forceinline__ u16 f2bf(float f) {
    uint32_t u = __float_as_uint(f);
    uint32_t r = (u + 0x7FFFu + ((u >> 16) & 1u)) >> 16;
    return (u16)r;
}

static __device__ __forceinline__ float sigmf(float x) {
    return 1.0f / (1.0f + __expf(-x));
}

static __device__ __forceinline__ float tanh_f(float x) {
    x = fminf(fmaxf(x, -20.f), 20.f);
    float e = __expf(2.f * x);
    return (e - 1.f) / (e + 1.f);
}

// Direct global->LDS 16B copy (dest is wave-uniform base + lane*16 in HW).
static __device__ __forceinline__ void gload16(const void* g, void* l) {
    __builtin_amdgcn_global_load_lds(
        (const __attribute__((address_space(1))) uint32_t*)g,
        (__attribute__((address_space(3))) uint32_t*)(uint32_t)(uintptr_t)l,
        16, 0, 0);
}

// Coherent 16B load: bypasses L1 and the (non-coherent) L2, reads the MALL
// coherence point — the same visibility path agent-scope atomic loads use.
static __device__ __forceinline__ u32x4 cload16(const void* p) {
    u32x4 r;
    asm volatile("global_load_dwordx4 %0, %1, off sc0 sc1" : "=v"(r) : "v"(p));
    return r;
}

// ---------------------------------------------------------------------------
// Fused prep (one launch, block-range roles):
//  [0, 16384):        W_comb; wx; biasc; zero flags; POISON Amir (sentinel)
//  [16384, 48384):    Wo = bf16(W_out)
//  [48384, 48896):    h0 = enc @ W_h^T (bf16), c0 = enc @ W_c^T (fp32)
// ---------------------------------------------------------------------------
__global__ void prep_fused(const float* __restrict__ Wih, const float* __restrict__ Whh,
                           const float* __restrict__ bih, const float* __restrict__ bhh,
                           const float* __restrict__ Wout,
                           const float* __restrict__ enc, const float* __restrict__ Wh,
                           const float* __restrict__ Wcp,
                           u16* __restrict__ Wc, float* __restrict__ wx,
                           float* __restrict__ biasc, unsigned* __restrict__ flags,
                           u16* __restrict__ Wo, u16* __restrict__ h0,
                           float* __restrict__ c0, unsigned* __restrict__ Amir32) {
    int blk = blockIdx.x;
    int tid = threadIdx.x;

    if (blk < 16384) {
        int idx = blk * 256 + tid;                 // 4096*1024 threads
        int r = idx >> 10, k = idx & 1023;
        float v = Wih[r * (H_ + 1) + 1 + k] + Whh[idx];
        Wc[idx] = f2bf(v);
        if (k == 0) {
            wx[r] = Wih[r * (H_ + 1)];
            biasc[r] = bih[r] + bhh[r];
        }
        if (idx < 2048) flags[idx] = 0u;           // re-zero every replay
        if (idx < 2097152) Amir32[idx] = 0xFFFFFFFFu;   // re-poison every replay
        return;
    }
    if (blk < 48384) {
        long long i = (long long)(blk - 16384) * 256 + tid;   // x4 elements
        f32x4 v = *(const f32x4*)(Wout + i * 4);
        uint2 o;
        o.x = (uint32_t)f2bf(v[0]) | ((uint32_t)f2bf(v[1]) << 16);
        o.y = (uint32_t)f2bf(v[2]) | ((uint32_t)f2bf(v[3]) << 16);
        *(uint2*)(Wo + i * 4) = o;
        return;
    }
    {
        int gwid = (blk - 48384) * 4 + (tid >> 6);   // 2048 waves
        int lane = tid & 63;
        int sel = gwid >> 10;                // 0: h, 1: c
        int j = gwid & 1023;
        const float* W = sel ? Wcp : Wh;
        const float* wrow = W + (size_t)j * H_;
        f32x4 wv[4];
#pragma unroll
        for (int it = 0; it < 4; ++it)
            wv[it] = *(const f32x4*)(wrow + it * 256 + lane * 4);
#pragma unroll 2
        for (int b = 0; b < B_; ++b) {
            const float* erow = enc + (size_t)b * H_;
            float acc = 0.f;
#pragma unroll
            for (int it = 0; it < 4; ++it) {
                f32x4 ev = *(const f32x4*)(erow + it * 256 + lane * 4);
                acc += wv[it][0] * ev[0] + wv[it][1] * ev[1] + wv[it][2] * ev[2] + wv[it][3] * ev[3];
            }
#pragma unroll
            for (int s = 32; s >= 1; s >>= 1) acc += __shfl_xor(acc, s, 64);
            if (lane == 0) {
                if (sel) c0[(size_t)b * H_ + j] = acc;
                else     h0[(size_t)b * H_ + j] = f2bf(acc);
            }
        }
    }
}

// ---------------------------------------------------------------------------
// FUSED kernel. Blocks 0..63 = recurrence with SENTINEL-POLL sync: consumers
// poll the mirrored h data itself (coherent loads); no per-step flags or
// drain barriers. One LDS barrier/step (red double-buffered). Gemm gating via
// coarse per-block counters incremented (post-drain) every 32 steps.
// Blocks 64..2063 = gated output GEMM (256x256 8-phase, m-tile 32t x 8b).
// ---------------------------------------------------------------------------
__global__ __launch_bounds__(512, 1) void fused_all(
    const u16* __restrict__ Wc, const float* __restrict__ wx,
    const float* __restrict__ biasc, const u16* __restrict__ h0,
    const float* __restrict__ c0, const float* __restrict__ y,
    u16* __restrict__ A, unsigned* __restrict__ flags,
    const u16* __restrict__ Wo, const float* __restrict__ bout,
    float* __restrict__ out, u16* __restrict__ Amir) {
    __shared__ __align__(16) u16 sb[77184];   // 154,368 B (rec role uses all)

    int tid = threadIdx.x;
    int lane = tid & 63;

    if (blockIdx.x < NBLK_REC) {
        // ================= recurrence =====================================
        __builtin_amdgcn_s_setprio(2);
        float* red = (float*)sb;             // [2][8][64*33] = 33792 f
        float* cs  = red + 2 * 8 * 2112;     // [16][33]
        float* wxs = cs + 16 * 33;           // [64]
        float* bcs = wxs + 64;               // [64]
        float* ys  = bcs + 64;               // [32][129]

        int kw = tid >> 6;                   // wave id = K-slice
        int bid = blockIdx.x;
        int j0 = bid * 16;
        int jl = lane & 15;
        int kc = (lane >> 4) * 8;
        int jlx = tid & 15, pb = tid >> 4;   // pointwise: 1 (j,b) per thread

        short8 afr[4][4];
        {
            const u16* abase = Wc + (size_t)(j0 + jl) * H_ + kw * 128 + kc;
#pragma unroll
            for (int g = 0; g < 4; ++g)
#pragma unroll
                for (int ks = 0; ks < 4; ++ks)
                    afr[g][ks] = *(const short8*)(abase + (size_t)g * H_ * H_ + ks * 32);
        }
#pragma unroll
        for (int g = 0; g < 4; ++g)
#pragma unroll
            for (int ks = 0; ks < 4; ++ks)
                asm volatile("" : "+v"(afr[g][ks]));   // pin: defeat remat

        if (tid < 64) {
            int g = tid >> 4, qq = tid & 15;
            wxs[tid] = wx[(size_t)g * H_ + j0 + qq];
            bcs[tid] = biasc[(size_t)g * H_ + j0 + qq];
        }
#pragma unroll
        for (int i = tid; i < B_ * T_; i += 512)
            ys[(i >> 7) * 129 + (i & 127)] = y[i];
        cs[jlx * 33 + pb] = c0[(size_t)pb * H_ + j0 + jlx];
        __syncthreads();

        for (int t = 0; t < T_; ++t) {
            short8 bf0[4], bf1[4];
            if (t == 0) {
                const u16* hb = h0 + (size_t)jl * H_ + kw * 128 + kc;
#pragma unroll
                for (int ks = 0; ks < 4; ++ks) {
                    bf0[ks] = *(const short8*)(hb + ks * 32);
                    bf1[ks] = *(const short8*)(hb + (size_t)16 * H_ + ks * 32);
                }
            } else {
                // ---- sentinel poll: the data IS the flag ----
                const u16* hb = Amir + ((size_t)(t - 1) * B_ + jl) * H_ + kw * 128 + kc;
                u32x4 q0[4], q1[4];
                int guard = 0;
                for (;;) {
#pragma unroll
                    for (int ks = 0; ks < 4; ++ks) {
                        q0[ks] = cload16(hb + ks * 32);
                        q1[ks] = cload16(hb + (size_t)16 * H_ + ks * 32);
                    }
                    asm volatile("s_waitcnt vmcnt(0)" ::: "memory");
                    __builtin_amdgcn_sched_barrier(0);
                    unsigned bad = 0;
#pragma unroll
                    for (int ks = 0; ks < 4; ++ks)
#pragma unroll
                        for (int d = 0; d < 4; ++d)
                            bad |= (unsigned)(q0[ks][d] == 0xFFFFFFFFu) |
                                   (unsigned)(q1[ks][d] == 0xFFFFFFFFu);
                    if (!__any(bad) || ++guard > 50000) break;   // hang-safety
                }
#pragma unroll
                for (int ks = 0; ks < 4; ++ks) {
                    bf0[ks] = __builtin_bit_cast(short8, q0[ks]);
                    bf1[ks] = __builtin_bit_cast(short8, q1[ks]);
                }
            }

            f32x4 acc[4][2] = {};
#pragma unroll
            for (int ks = 0; ks < 4; ++ks) {
#pragma unroll
                for (int g = 0; g < 4; ++g) {
                    acc[g][0] = __builtin_amdgcn_mfma_f32_16x16x32_bf16(afr[g][ks], bf0[ks], acc[g][0], 0, 0, 0);
                    acc[g][1] = __builtin_amdgcn_mfma_f32_16x16x32_bf16(afr[g][ks], bf1[ks], acc[g][1], 0, 0, 0);
                }
            }
            float* redp = red + (t & 1) * 16896;
            int r0 = (lane >> 4) * 4;
#pragma unroll
            for (int g = 0; g < 4; ++g)
#pragma unroll
                for (int bt = 0; bt < 2; ++bt)
#pragma unroll
                    for (int r = 0; r < 4; ++r)
                        redp[kw * 2112 + (g * 16 + r0 + r) * 33 + bt * 16 + jl] = acc[g][bt][r];
            // one barrier per step: red RAW (no vmcnt drain — raw s_barrier)
            asm volatile("s_waitcnt lgkmcnt(0)" ::: "memory");
            __builtin_amdgcn_s_barrier();

            // ---- pointwise: one (jlx, pb) per thread ----
            {
                float yv = ys[pb * 129 + t];
                float pg[4];
#pragma unroll
                for (int g = 0; g < 4; ++g) {
                    int row = (g * 16 + jlx) * 33 + pb;
                    float sum = redp[row];
#pragma unroll
                    for (int ww = 1; ww < 8; ++ww) sum += redp[ww * 2112 + row];
                    pg[g] = sum + wxs[g * 16 + jlx] * yv + bcs[g * 16 + jlx];
                }
                float iv = sigmf(pg[0]);
                float fv = sigmf(pg[1]);
                float gv = tanh_f(pg[2]);
                float ov = sigmf(pg[3]);
                float cv = fv * cs[jlx * 33 + pb] + iv * gv;
                cs[jlx * 33 + pb] = cv;
                float hv = ov * tanh_f(cv);

                unsigned h16 = (unsigned)f2bf(hv);
                unsigned oth = (unsigned)__shfl((int)h16, lane + 1, 64);  // jlx+1 partner
                if (!(jlx & 1)) {
                    uint32_t pk = h16 | (oth << 16);
                    size_t off = ((size_t)t * B_ + pb) * H_ + j0 + jlx;
                    __hip_atomic_store((uint32_t*)(A + off), pk,
                                       __ATOMIC_RELAXED, __HIP_MEMORY_SCOPE_AGENT);
                    __hip_atomic_store((uint32_t*)(Amir + off), pk,
                                       __ATOMIC_RELAXED, __HIP_MEMORY_SCOPE_AGENT);
                }
            }
            // coarse gemm signal: every 32 steps, drain own stores then count
            if (((t + 1) & 31) == 0) {
                asm volatile("s_waitcnt vmcnt(0)" ::: "memory");
                if (lane == 0)
                    __hip_atomic_fetch_add(&flags[bid * 32], 1u,
                                           __ATOMIC_RELAXED, __HIP_MEMORY_SCOPE_AGENT);
            }
        }
        return;
    }

    // ================= gated output GEMM ==================================
    // m-tile = 32 t x 8 b: global m-row R: b = bb*8 + (R>>5), t = tb*32 + (R&31).
    // 4 gate groups of 500 blocks (tb = 0..3), gate target cnt >= 8*(tb+1).
    int orig = blockIdx.x - NBLK_REC;         // 0..1999
    int tb = orig / 500;                      // gate group, dispatch-ascending
    int wp = orig - tb * 500;
    int xcd = wp & 7, rest = wp >> 3;         // bijective swizzle: 500 = 8*62+4
    int wg = (xcd < 4 ? xcd * 63 : 252 + (xcd - 4) * 62) + rest;
    int bb = wg / 125;                        // 0..3
    int nb = wg - bb * 125;                   // 0..124
    int n0g = nb << 8;

    int wid = tid >> 6;
    int wm = wid >> 2, wn = wid & 3;
    int jl = lane & 15, kq = lane >> 4;

    f32x4 acc[8][4] = {};

    // stage half-tile h (0=A0,1=A1,2=B0,3=B1) of K-tile `tile`
    auto stage = [&](int tile, int h) {
        u16* dst = sb + ((tile & 1) << 15) + (h << 13) + tid * 8;
#pragma unroll
        for (int ld = 0; ld < 2; ++ld) {
            int p = tid + (ld << 9);
            int row = p >> 3;
            int c16 = (p & 7) ^ (row & 7);        // inverse-swizzled source
            const u16* src;
            if (h < 2)
                src = A + ((size_t)(tb * 32 + (row & 31)) * B_
                           + (size_t)(bb * 8 + h * 4 + (row >> 5))) * H_
                        + tile * 64 + c16 * 8;
            else
                src = Wo + (size_t)(n0g + ((h - 2) << 7) + row) * H_
                         + tile * 64 + c16 * 8;
            gload16(src, dst + (ld << 12));
        }
    };

    // pre-gate: warm the B panels of tile 0 (Wo ready from prep_fused)
    stage(0, 2); stage(0, 3);

    // ---- gate: wave 0 polls all 64 producer counters; others park ----
    if (wid == 0) {
        unsigned target = 8u * (unsigned)(tb + 1);
        const unsigned* fp = &flags[lane * 32];
        int guard = 0;
        for (;;) {
            unsigned v = __hip_atomic_load(fp, __ATOMIC_RELAXED, __HIP_MEMORY_SCOPE_AGENT);
            if (__all(v >= target)) break;
            __builtin_amdgcn_s_sleep(32);
            if (++guard > 20000000) break;   // hang-safety
        }
        __atomic_signal_fence(__ATOMIC_ACQUIRE);
    }
    __builtin_amdgcn_s_barrier();

    // ---- prologue: A of tile0 + A0,B0 of tile1; leave 4 in flight ----
    stage(0, 0); stage(0, 1); stage(1, 0); stage(1, 2);
    asm volatile("s_waitcnt vmcnt(4)" ::: "memory");
    __builtin_amdgcn_s_barrier();

    const int NT = 16;   // K/64
    for (int tile = 0; tile < NT; ++tile) {
        const u16* buf = sb + ((tile & 1) << 15);
#pragma unroll
        for (int q = 0; q < 4; ++q) {
            const int mh = q >> 1, nh = q & 1;
            short8 af[4][2], bfr[2][2];
            const u16* bufA = buf + (mh << 13);
            const u16* bufB = buf + (1 << 14) + (nh << 13);
#pragma unroll
            for (int i = 0; i < 4; ++i) {
                int row = wm * 64 + (i << 4) + jl;
                int rx = (row & 7) << 3;
#pragma unroll
                for (int k2 = 0; k2 < 2; ++k2)
                    af[i][k2] = *(const short8*)(bufA + row * 64 + (((k2 << 5) + (kq << 3)) ^ rx));
            }
#pragma unroll
            for (int i = 0; i < 2; ++i) {
                int row = wn * 32 + (i << 4) + jl;
                int rx = (row & 7) << 3;
#pragma unroll
                for (int k2 = 0; k2 < 2; ++k2)
                    bfr[i][k2] = *(const short8*)(bufB + row * 64 + (((k2 << 5) + (kq << 3)) ^ rx));
            }
            if (q == 0) { if (tile + 1 < NT) stage(tile + 1, 1); }
            if (q == 1) { if (tile + 1 < NT) stage(tile + 1, 3); }
            if (q == 2) { if (tile + 2 < NT) stage(tile + 2, 0); }
            if (q == 3) { if (tile + 2 < NT) stage(tile + 2, 2); }

            asm volatile("" ::: "memory");
            __builtin_amdgcn_s_barrier();
            asm volatile("" ::: "memory");
            __builtin_amdgcn_s_setprio(1);
#pragma unroll
            for (int i = 0; i < 4; ++i)
#pragma unroll
                for (int jn = 0; jn < 2; ++jn)
#pragma unroll
                    for (int k2 = 0; k2 < 2; ++k2)
                        acc[mh * 4 + i][nh * 2 + jn] =
                            __builtin_amdgcn_mfma_f32_16x16x32_bf16(
                                af[i][k2], bfr[jn][k2], acc[mh * 4 + i][nh * 2 + jn], 0, 0, 0);
            __builtin_amdgcn_s_setprio(0);
            if (q == 3) {
                if (tile < 14) asm volatile("s_waitcnt vmcnt(4)" ::: "memory");
                else           asm volatile("s_waitcnt vmcnt(0)" ::: "memory");
            }
            asm volatile("" ::: "memory");
            __builtin_amdgcn_s_barrier();
        }
    }

    // ---- epilogue: fragment = one b x 16 consecutive t -> direct stores ----
#pragma unroll
    for (int nt = 0; nt < 4; ++nt) {
        int n = n0g + ((nt >> 1) << 7) + wn * 32 + ((nt & 1) << 4) + jl;
        float bias = bout[n];
#pragma unroll
        for (int mt = 0; mt < 8; ++mt) {
            int mh = mt >> 2, i = mt & 3;
            int bo = bb * 8 + mh * 4 + wm * 2 + (i >> 1);
            f32x4 v = acc[mt][nt];
            v[0] += bias; v[1] += bias; v[2] += bias; v[3] += bias;
            float* dst = out + ((size_t)bo * V_ + n) * T_ + tb * 32 + ((i & 1) << 4) + (kq << 2);
            *(f32x4*)dst = v;
        }
    }
}

// ---------------------------------------------------------------------------
extern "C" void kernel_launch(void* const* d_in, const int* in_sizes, int n_in,
                              void* d_out, int out_size, void* d_ws, size_t ws_size,
                              hipStream_t stream) {
    const float* y    = (const float*)d_in[0];   // [B,T]
    const float* enc  = (const float*)d_in[1];   // [B,H]
    const float* Wh   = (const float*)d_in[2];   // [H,H]
    const float* Wcp  = (const float*)d_in[3];   // [H,H]
    const float* Wih  = (const float*)d_in[4];   // [4H,1+H]
    const float* Whh  = (const float*)d_in[5];   // [4H,H]
    const float* bih  = (const float*)d_in[6];   // [4H]
    const float* bhh  = (const float*)d_in[7];   // [4H]
    const float* Wout = (const float*)d_in[8];   // [V,H]
    const float* bout = (const float*)d_in[9];   // [V]

    uint8_t* ws = (uint8_t*)d_ws;
    u16*  Wcomb = (u16*)ws;                                   // 8,388,608 B
    u16*  Wo    = (u16*)(ws + 8388608);                       // 65,536,000 B
    float* wx    = (float*)(ws + 8388608 + 65536000);
    float* biasc = wx + 4096;
    u16*  h0    = (u16*)(biasc + 4096);
    float* c     = (float*)(h0 + 32 * 1024);
    u16*  A     = (u16*)(c + 32 * 1024);                      // [T][B][H] bf16
    unsigned* flags = (unsigned*)(A + (size_t)4096 * 1024);   // 2048*4 B (line-spread)
    u16*  Amir  = (u16*)(flags + 2048);                       // [T][B][H] bf16 mirror

    prep_fused<<<48896, 256, 0, stream>>>(Wih, Whh, bih, bhh, Wout, enc, Wh, Wcp,
                                          Wcomb, wx, biasc, flags, Wo, h0, c,
                                          (unsigned*)Amir);

    fused_all<<<NBLK_REC + 2000, 512, 0, stream>>>(
        Wcomb, wx, biasc, h0, c, y, A, flags, Wo, bout, (float*)d_out, Amir);
}

// Round 14
// 780.401 us; speedup vs baseline: 1.3349x; 1.3349x over previous
//
#include <hip/hip_runtime.h>
#include <hip/hip_bf16.h>
#include <stdint.h>

#define B_ 32
#define T_ 128
#define H_ 1024
#define V_ 32000
#define NBLK_REC 64

typedef unsigned short u16;
typedef __attribute__((ext_vector_type(8))) short short8;
typedef __attribute__((ext_vector_type(4))) float f32x4;

static __device__ __forceinline__ u16 f2bf(float f) {
    uint32_t u = __float_as_uint(f);
    uint32_t r = (u + 0x7FFFu + ((u >> 16) & 1u)) >> 16;
    return (u16)r;
}

static __device__ __forceinline__ float sigmf(float x) {
    return 1.0f / (1.0f + __expf(-x));
}

static __device__ __forceinline__ float tanh_f(float x) {
    x = fminf(fmaxf(x, -20.f), 20.f);
    float e = __expf(2.f * x);
    return (e - 1.f) / (e + 1.f);
}

// Direct global->LDS 16B copy (dest is wave-uniform base + lane*16 in HW).
static __device__ __forceinline__ void gload16(const void* g, void* l) {
    __builtin_amdgcn_global_load_lds(
        (const __attribute__((address_space(1))) uint32_t*)g,
        (__attribute__((address_space(3))) uint32_t*)(uint32_t)(uintptr_t)l,
        16, 0, 0);
}

// ---------------------------------------------------------------------------
// Tiny per-replay reset: zero block flags (64 lines) + conv flags (64 lines).
// ---------------------------------------------------------------------------
__global__ void zero_flags(unsigned* __restrict__ flags) {
    int idx = blockIdx.x * 256 + threadIdx.x;   // 4096 dwords
    flags[idx] = 0u;
}

// ---------------------------------------------------------------------------
// ONE fused kernel.
//  Blocks 0..63   : persistent LSTM recurrence (r12 protocol). Self-prep:
//                   converts own weight rows fp32->bf16 into registers,
//                   computes wx/biasc/c0 locally, computes h0 and publishes
//                   it as A slot 0. A = [T+1][B][H], flag = slot+1.
//  Blocks 64..2063: gated output GEMM (256x256 8-phase, m-tile 32t x 8b,
//                   4 gate groups of 500). Blocks orig 0..127 (co-resident
//                   with the recurrence from dispatch) first convert
//                   Wout fp32 -> Wo bf16 (250 rows each, agent stores),
//                   signalled on 64 spread lines (2 increments each).
// ---------------------------------------------------------------------------
__global__ __launch_bounds__(512, 2) void fused_all(
    const float* __restrict__ Wih, const float* __restrict__ Whh,
    const float* __restrict__ bih, const float* __restrict__ bhh,
    const float* __restrict__ enc, const float* __restrict__ Wh,
    const float* __restrict__ Wcp, const float* __restrict__ Wout,
    const float* __restrict__ y,
    u16* __restrict__ A, unsigned* __restrict__ flags,
    u16* __restrict__ Wo, const float* __restrict__ bout,
    float* __restrict__ out) {
    __shared__ __align__(16) u16 sb[65536];   // 128KB pool (both roles)

    int tid = threadIdx.x;
    int lane = tid & 63;

    if (blockIdx.x < NBLK_REC) {
        // ================= recurrence =====================================
        __builtin_amdgcn_s_setprio(2);
        float* red = (float*)sb;             // [8][64*33] = 16896 f
        float* cs  = red + 8 * 2112;         // [16][33]
        float* wxs = cs + 16 * 33;           // [64]
        float* bcs = wxs + 64;               // [64]
        float* ys  = bcs + 64;               // [32][129]

        int kw = tid >> 6;                   // wave id = K-slice
        int bid = blockIdx.x;
        int j0 = bid * 16;
        int jl = lane & 15;
        int kc = (lane >> 4) * 8;
        int jlx = tid & 15, pb = tid >> 4;   // pointwise: 1 (j,b) per thread

        // ---- self-prep: convert own weight slice fp32 -> bf16 registers ----
        short8 afr[4][4];
#pragma unroll
        for (int g = 0; g < 4; ++g)
#pragma unroll
            for (int ks = 0; ks < 4; ++ks) {
                int row = g * H_ + j0 + jl;
                const float* pih = Wih + (size_t)row * (H_ + 1) + 1 + kw * 128 + kc + ks * 32;
                const float* phh = Whh + (size_t)row * H_ + kw * 128 + kc + ks * 32;
                short8 s;
#pragma unroll
                for (int e = 0; e < 8; ++e)
                    s[e] = (short)f2bf(pih[e] + phh[e]);
                afr[g][ks] = s;
            }
#pragma unroll
        for (int g = 0; g < 4; ++g)
#pragma unroll
            for (int ks = 0; ks < 4; ++ks)
                asm volatile("" : "+v"(afr[g][ks]));   // pin: defeat remat

        if (tid < 64) {
            int row = (tid >> 4) * H_ + j0 + (tid & 15);
            wxs[tid] = Wih[(size_t)row * (H_ + 1)];
            bcs[tid] = bih[row] + bhh[row];
        }
#pragma unroll
        for (int i = tid; i < B_ * T_; i += 512)
            ys[(i >> 7) * 129 + (i & 127)] = y[i];

        // ---- self-init: h0, c0 for own (jlx, pb); publish h0 as A slot 0 ----
        {
            const float* er  = enc + (size_t)pb * H_;
            const float* whr = Wh  + (size_t)(j0 + jlx) * H_;
            const float* wcr = Wcp + (size_t)(j0 + jlx) * H_;
            f32x4 ah = {0.f, 0.f, 0.f, 0.f}, ac = {0.f, 0.f, 0.f, 0.f};
#pragma unroll 4
            for (int k4 = 0; k4 < H_ / 4; ++k4) {
                f32x4 ev = *(const f32x4*)(er + k4 * 4);
                ah += ev * (*(const f32x4*)(whr + k4 * 4));
                ac += ev * (*(const f32x4*)(wcr + k4 * 4));
            }
            cs[jlx * 33 + pb] = ac[0] + ac[1] + ac[2] + ac[3];
            float h0v = ah[0] + ah[1] + ah[2] + ah[3];
            unsigned h16 = (unsigned)f2bf(h0v);
            unsigned oth = (unsigned)__shfl((int)h16, lane + 1, 64);
            if (!(jlx & 1)) {
                uint32_t pk = h16 | (oth << 16);
                __hip_atomic_store((uint32_t*)(A + (size_t)pb * H_ + j0 + jlx),
                                   pk, __ATOMIC_RELAXED, __HIP_MEMORY_SCOPE_AGENT);
            }
        }
        __syncthreads();   // drains vmcnt: h0 stores visible; LDS init done
        if (tid == 0)
            __hip_atomic_store(&flags[bid * 32], 1u,
                               __ATOMIC_RELAXED, __HIP_MEMORY_SCOPE_AGENT);

        for (int t = 0; t < T_; ++t) {
            // ---- wait for slot t (= h_{t-1}): 8 producers, own 128B lines --
            {
                const unsigned* fp = &flags[(kw * 8 + (lane & 7)) * 32];
                unsigned target = (unsigned)(t + 1);
                int guard = 0;
                for (;;) {
                    unsigned v = __hip_atomic_load(fp, __ATOMIC_RELAXED, __HIP_MEMORY_SCOPE_AGENT);
                    if (__all(v >= target)) break;
                    if (++guard > 20000000) break;
                }
                __atomic_signal_fence(__ATOMIC_ACQUIRE);
            }

            short8 bf0[4], bf1[4];
            {
                const u16* hb = A + ((size_t)t * B_ + jl) * H_ + kw * 128 + kc;
#pragma unroll
                for (int ks = 0; ks < 4; ++ks) {
                    bf0[ks] = *(const short8*)(hb + ks * 32);
                    bf1[ks] = *(const short8*)(hb + (size_t)16 * H_ + ks * 32);
                }
            }
            f32x4 acc[4][2] = {};
#pragma unroll
            for (int ks = 0; ks < 4; ++ks) {
#pragma unroll
                for (int g = 0; g < 4; ++g) {
                    acc[g][0] = __builtin_amdgcn_mfma_f32_16x16x32_bf16(afr[g][ks], bf0[ks], acc[g][0], 0, 0, 0);
                    acc[g][1] = __builtin_amdgcn_mfma_f32_16x16x32_bf16(afr[g][ks], bf1[ks], acc[g][1], 0, 0, 0);
                }
            }
            int r0 = (lane >> 4) * 4;
#pragma unroll
            for (int g = 0; g < 4; ++g)
#pragma unroll
                for (int bt = 0; bt < 2; ++bt)
#pragma unroll
                    for (int r = 0; r < 4; ++r)
                        red[kw * 2112 + (g * 16 + r0 + r) * 33 + bt * 16 + jl] = acc[g][bt][r];
            __syncthreads();   // red RAW

            // ---- pointwise: every thread does ONE (jlx, pb) ----
            {
                float yv = ys[pb * 129 + t];
                float pg[4];
#pragma unroll
                for (int g = 0; g < 4; ++g) {
                    int row = (g * 16 + jlx) * 33 + pb;
                    float sum = red[row];
#pragma unroll
                    for (int ww = 1; ww < 8; ++ww) sum += red[ww * 2112 + row];
                    pg[g] = sum + wxs[g * 16 + jlx] * yv + bcs[g * 16 + jlx];
                }
                float iv = sigmf(pg[0]);
                float fv = sigmf(pg[1]);
                float gv = tanh_f(pg[2]);
                float ov = sigmf(pg[3]);
                float cv = fv * cs[jlx * 33 + pb] + iv * gv;
                cs[jlx * 33 + pb] = cv;
                float hv = ov * tanh_f(cv);

                unsigned h16 = (unsigned)f2bf(hv);
                unsigned oth = (unsigned)__shfl((int)h16, lane + 1, 64);
                if (!(jlx & 1)) {
                    uint32_t pk = h16 | (oth << 16);
                    __hip_atomic_store((uint32_t*)(A + ((size_t)(t + 1) * B_ + pb) * H_ + j0 + jlx),
                                       pk, __ATOMIC_RELAXED, __HIP_MEMORY_SCOPE_AGENT);
                }
            }
            // Barrier drains every thread's vmcnt -> slot t+1 stores visible.
            __syncthreads();
            if (tid == 0)
                __hip_atomic_store(&flags[bid * 32], (unsigned)(t + 2),
                                   __ATOMIC_RELAXED, __HIP_MEMORY_SCOPE_AGENT);
        }
        return;
    }

    // ================= gated output GEMM ==================================
    int orig = blockIdx.x - NBLK_REC;         // 0..1999
    int tb = orig / 500;                      // gate group, dispatch-ascending
    int wp = orig - tb * 500;
    int xcd = wp & 7, rest = wp >> 3;         // bijective swizzle: 500 = 8*62+4
    int wg = (xcd < 4 ? xcd * 63 : 252 + (xcd - 4) * 62) + rest;
    int bb = wg / 125;                        // 0..3
    int nb = wg - bb * 125;                   // 0..124
    int n0g = nb << 8;

    int wid = tid >> 6;
    int wm = wid >> 2, wn = wid & 3;
    int jl = lane & 15, kq = lane >> 4;

    // ---- converter duty: orig 0..127 convert 250 Wout rows each ----
    if (orig < 128) {
        const int QP = 250 * H_ / 4;          // 64000 quads per block
        long long qbase = (long long)orig * QP;
        for (int i = tid; i < QP; i += 512) {
            long long q = qbase + i;
            f32x4 v = *(const f32x4*)(Wout + q * 4);
            unsigned long long pk =
                (unsigned long long)((uint32_t)f2bf(v[0]) | ((uint32_t)f2bf(v[1]) << 16)) |
                ((unsigned long long)((uint32_t)f2bf(v[2]) | ((uint32_t)f2bf(v[3]) << 16)) << 32);
            __hip_atomic_store((unsigned long long*)Wo + q, pk,
                               __ATOMIC_RELAXED, __HIP_MEMORY_SCOPE_AGENT);
        }
        asm volatile("s_waitcnt vmcnt(0)" ::: "memory");
        __syncthreads();
        if (tid == 0)
            __hip_atomic_fetch_add(&flags[2048 + (orig & 63) * 32], 1u,
                                   __ATOMIC_RELAXED, __HIP_MEMORY_SCOPE_AGENT);
    }

    // ---- conv gate: Wo fully converted (64 lines, target 2 each) ----
    if (wid == 0) {
        const unsigned* fp = &flags[2048 + lane * 32];
        int guard = 0;
        for (;;) {
            unsigned v = __hip_atomic_load(fp, __ATOMIC_RELAXED, __HIP_MEMORY_SCOPE_AGENT);
            if (__all(v >= 2u)) break;
            __builtin_amdgcn_s_sleep(16);
            if (++guard > 20000000) break;   // hang-safety
        }
        __atomic_signal_fence(__ATOMIC_ACQUIRE);
    }
    __builtin_amdgcn_s_barrier();

    f32x4 acc[8][4] = {};

    // stage half-tile h (0=A0,1=A1,2=B0,3=B1) of K-tile `tile`
    auto stage = [&](int tile, int h) {
        u16* dst = sb + ((tile & 1) << 15) + (h << 13) + tid * 8;
#pragma unroll
        for (int ld = 0; ld < 2; ++ld) {
            int p = tid + (ld << 9);
            int row = p >> 3;
            int c16 = (p & 7) ^ (row & 7);        // inverse-swizzled source
            const u16* src;
            if (h < 2)   // A slot = t+1 (h_t at slot t+1)
                src = A + ((size_t)(tb * 32 + (row & 31) + 1) * B_
                           + (size_t)(bb * 8 + h * 4 + (row >> 5))) * H_
                        + tile * 64 + c16 * 8;
            else
                src = Wo + (size_t)(n0g + ((h - 2) << 7) + row) * H_
                         + tile * 64 + c16 * 8;
            gload16(src, dst + (ld << 12));
        }
    };

    // warm the B panels of tile 0 (Wo converted; recurrence gate is far off)
    stage(0, 2); stage(0, 3);

    // ---- gate: wave 0 polls all 64 producer block-flag lines; others park --
    if (wid == 0) {
        unsigned target = (unsigned)(tb * 32 + 33);   // slot 32(tb+1) stored
        const unsigned* fp = &flags[lane * 32];
        int guard = 0;
        for (;;) {
            unsigned v = __hip_atomic_load(fp, __ATOMIC_RELAXED, __HIP_MEMORY_SCOPE_AGENT);
            if (__all(v >= target)) break;
            __builtin_amdgcn_s_sleep(32);
            if (++guard > 20000000) break;   // hang-safety
        }
        __atomic_signal_fence(__ATOMIC_ACQUIRE);
    }
    __builtin_amdgcn_s_barrier();

    // ---- prologue: A of tile0 + A0,B0 of tile1; leave 4 in flight ----
    stage(0, 0); stage(0, 1); stage(1, 0); stage(1, 2);
    asm volatile("s_waitcnt vmcnt(4)" ::: "memory");
    __builtin_amdgcn_s_barrier();

    const int NT = 16;   // K/64
    for (int tile = 0; tile < NT; ++tile) {
        const u16* buf = sb + ((tile & 1) << 15);
#pragma unroll
        for (int q = 0; q < 4; ++q) {
            const int mh = q >> 1, nh = q & 1;
            short8 af[4][2], bfr[2][2];
            const u16* bufA = buf + (mh << 13);
            const u16* bufB = buf + (1 << 14) + (nh << 13);
#pragma unroll
            for (int i = 0; i < 4; ++i) {
                int row = wm * 64 + (i << 4) + jl;
                int rx = (row & 7) << 3;
#pragma unroll
                for (int k2 = 0; k2 < 2; ++k2)
                    af[i][k2] = *(const short8*)(bufA + row * 64 + (((k2 << 5) + (kq << 3)) ^ rx));
            }
#pragma unroll
            for (int i = 0; i < 2; ++i) {
                int row = wn * 32 + (i << 4) + jl;
                int rx = (row & 7) << 3;
#pragma unroll
                for (int k2 = 0; k2 < 2; ++k2)
                    bfr[i][k2] = *(const short8*)(bufB + row * 64 + (((k2 << 5) + (kq << 3)) ^ rx));
            }
            if (q == 0) { if (tile + 1 < NT) stage(tile + 1, 1); }
            if (q == 1) { if (tile + 1 < NT) stage(tile + 1, 3); }
            if (q == 2) { if (tile + 2 < NT) stage(tile + 2, 0); }
            if (q == 3) { if (tile + 2 < NT) stage(tile + 2, 2); }

            asm volatile("" ::: "memory");
            __builtin_amdgcn_s_barrier();
            asm volatile("" ::: "memory");
            __builtin_amdgcn_s_setprio(1);
#pragma unroll
            for (int i = 0; i < 4; ++i)
#pragma unroll
                for (int jn = 0; jn < 2; ++jn)
#pragma unroll
                    for (int k2 = 0; k2 < 2; ++k2)
                        acc[mh * 4 + i][nh * 2 + jn] =
                            __builtin_amdgcn_mfma_f32_16x16x32_bf16(
                                af[i][k2], bfr[jn][k2], acc[mh * 4 + i][nh * 2 + jn], 0, 0, 0);
            __builtin_amdgcn_s_setprio(0);
            if (q == 3) {
                if (tile < 14) asm volatile("s_waitcnt vmcnt(4)" ::: "memory");
                else           asm volatile("s_waitcnt vmcnt(0)" ::: "memory");
            }
            asm volatile("" ::: "memory");
            __builtin_amdgcn_s_barrier();
        }
    }

    // ---- epilogue: fragment = one b x 16 consecutive t -> direct stores ----
#pragma unroll
    for (int nt = 0; nt < 4; ++nt) {
        int n = n0g + ((nt >> 1) << 7) + wn * 32 + ((nt & 1) << 4) + jl;
        float bias = bout[n];
#pragma unroll
        for (int mt = 0; mt < 8; ++mt) {
            int mh = mt >> 2, i = mt & 3;
            int bo = bb * 8 + mh * 4 + wm * 2 + (i >> 1);
            f32x4 v = acc[mt][nt];
            v[0] += bias; v[1] += bias; v[2] += bias; v[3] += bias;
            float* dst = out + ((size_t)bo * V_ + n) * T_ + tb * 32 + ((i & 1) << 4) + (kq << 2);
            *(f32x4*)dst = v;
        }
    }
}

// ---------------------------------------------------------------------------
extern "C" void kernel_launch(void* const* d_in, const int* in_sizes, int n_in,
                              void* d_out, int out_size, void* d_ws, size_t ws_size,
                              hipStream_t stream) {
    const float* y    = (const float*)d_in[0];   // [B,T]
    const float* enc  = (const float*)d_in[1];   // [B,H]
    const float* Wh   = (const float*)d_in[2];   // [H,H]
    const float* Wcp  = (const float*)d_in[3];   // [H,H]
    const float* Wih  = (const float*)d_in[4];   // [4H,1+H]
    const float* Whh  = (const float*)d_in[5];   // [4H,H]
    const float* bih  = (const float*)d_in[6];   // [4H]
    const float* bhh  = (const float*)d_in[7];   // [4H]
    const float* Wout = (const float*)d_in[8];   // [V,H]
    const float* bout = (const float*)d_in[9];   // [V]

    uint8_t* ws = (uint8_t*)d_ws;
    u16*  Wo    = (u16*)ws;                                   // 65,536,000 B
    u16*  A     = (u16*)(ws + 65536000);                      // [T+1][B][H] bf16 = 8,454,144 B
    unsigned* flags = (unsigned*)(ws + 65536000 + 8454144);   // 4096*4 B

    zero_flags<<<16, 256, 0, stream>>>(flags);

    fused_all<<<NBLK_REC + 2000, 512, 0, stream>>>(
        Wih, Whh, bih, bhh, enc, Wh, Wcp, Wout, y,
        A, flags, Wo, bout, (float*)d_out);
}

// Round 15
// 690.900 us; speedup vs baseline: 1.5079x; 1.1295x over previous
//
#include <hip/hip_runtime.h>
#include <hip/hip_bf16.h>
#include <stdint.h>

#define B_ 32
#define T_ 128
#define H_ 1024
#define V_ 32000
#define NBLK_REC 64

typedef unsigned short u16;
typedef __attribute__((ext_vector_type(8))) short short8;
typedef __attribute__((ext_vector_type(4))) float f32x4;

static __device__ __forceinline__ u16 f2bf(float f) {
    uint32_t u = __float_as_uint(f);
    uint32_t r = (u + 0x7FFFu + ((u >> 16) & 1u)) >> 16;
    return (u16)r;
}

static __device__ __forceinline__ float sigmf(float x) {
    return 1.0f / (1.0f + __expf(-x));
}

static __device__ __forceinline__ float tanh_f(float x) {
    x = fminf(fmaxf(x, -20.f), 20.f);
    float e = __expf(2.f * x);
    return (e - 1.f) / (e + 1.f);
}

// Direct global->LDS 16B copy (dest is wave-uniform base + lane*16 in HW).
static __device__ __forceinline__ void gload16(const void* g, void* l) {
    __builtin_amdgcn_global_load_lds(
        (const __attribute__((address_space(1))) uint32_t*)g,
        (__attribute__((address_space(3))) uint32_t*)(uint32_t)(uintptr_t)l,
        16, 0, 0);
}

// ---------------------------------------------------------------------------
// Serial prep (small): W_comb conversion + wx/biasc + flag zero + h0/c0 init.
// Wout conversion is NOT here — it moves into the fused kernel's gemm blocks
// (dead gate window). Grid = 16384 + 512 = 16896 blocks.
// ---------------------------------------------------------------------------
__global__ void prep_mid(const float* __restrict__ Wih, const float* __restrict__ Whh,
                         const float* __restrict__ bih, const float* __restrict__ bhh,
                         const float* __restrict__ enc, const float* __restrict__ Wh,
                         const float* __restrict__ Wcp,
                         u16* __restrict__ Wc, float* __restrict__ wx,
                         float* __restrict__ biasc, unsigned* __restrict__ flags,
                         u16* __restrict__ h0, float* __restrict__ c0) {
    int blk = blockIdx.x;
    int tid = threadIdx.x;

    if (blk < 16384) {
        int idx = blk * 256 + tid;                 // 4096*1024 threads
        int r = idx >> 10, k = idx & 1023;
        float v = Wih[r * (H_ + 1) + 1 + k] + Whh[idx];
        Wc[idx] = f2bf(v);
        if (k == 0) {
            wx[r] = Wih[r * (H_ + 1)];
            biasc[r] = bih[r] + bhh[r];
        }
        if (idx < 4096) flags[idx] = 0u;           // re-zero every replay
        return;
    }
    {
        int gwid = (blk - 16384) * 4 + (tid >> 6);   // 2048 waves
        int lane = tid & 63;
        int sel = gwid >> 10;                // 0: h, 1: c
        int j = gwid & 1023;
        const float* W = sel ? Wcp : Wh;
        const float* wrow = W + (size_t)j * H_;
        f32x4 wv[4];
#pragma unroll
        for (int it = 0; it < 4; ++it)
            wv[it] = *(const f32x4*)(wrow + it * 256 + lane * 4);
#pragma unroll 2
        for (int b = 0; b < B_; ++b) {
            const float* erow = enc + (size_t)b * H_;
            float acc = 0.f;
#pragma unroll
            for (int it = 0; it < 4; ++it) {
                f32x4 ev = *(const f32x4*)(erow + it * 256 + lane * 4);
                acc += wv[it][0] * ev[0] + wv[it][1] * ev[1] + wv[it][2] * ev[2] + wv[it][3] * ev[3];
            }
#pragma unroll
            for (int s = 32; s >= 1; s >>= 1) acc += __shfl_xor(acc, s, 64);
            if (lane == 0) {
                if (sel) c0[(size_t)b * H_ + j] = acc;
                else     h0[(size_t)b * H_ + j] = f2bf(acc);
            }
        }
    }
}

// ---------------------------------------------------------------------------
// FUSED kernel: blocks 0..63 = persistent LSTM recurrence (r12 protocol,
// proven 662us); blocks 64..2063 = gated output GEMM (256x256 8-phase,
// m-tile 32t x 8b, 4 gate groups of 500). Gemm blocks orig 0..127 first
// convert Wout fp32 -> Wo bf16 (250 rows each, agent stores — required for
// cross-XCD visibility), signalled on 64 spread lines (target 2 each).
// ---------------------------------------------------------------------------
__global__ __launch_bounds__(512, 2) void fused_all(
    const u16* __restrict__ Wc, const float* __restrict__ wx,
    const float* __restrict__ biasc, const u16* __restrict__ h0,
    const float* __restrict__ c0, const float* __restrict__ y,
    u16* __restrict__ A, unsigned* __restrict__ flags,
    u16* __restrict__ Wo, const float* __restrict__ Wout,
    const float* __restrict__ bout, float* __restrict__ out) {
    __shared__ __align__(16) u16 sb[65536];   // 128KB pool (both roles)

    int tid = threadIdx.x;
    int lane = tid & 63;

    if (blockIdx.x < NBLK_REC) {
        // ================= recurrence (r12 verbatim) ======================
        __builtin_amdgcn_s_setprio(2);       // latency-critical: outrank gemm
        float* red = (float*)sb;             // [8][64*33] = 16896 f
        float* cs  = red + 8 * 2112;         // [16][33]
        float* wxs = cs + 16 * 33;           // [64]
        float* bcs = wxs + 64;               // [64]
        float* ys  = bcs + 64;               // [32][129]

        int kw = tid >> 6;                   // wave id = K-slice
        int bid = blockIdx.x;
        int j0 = bid * 16;
        int jl = lane & 15;
        int kc = (lane >> 4) * 8;
        int jlx = tid & 15, pb = tid >> 4;   // pointwise: 1 (j,b) per thread

        short8 afr[4][4];
        {
            const u16* abase = Wc + (size_t)(j0 + jl) * H_ + kw * 128 + kc;
#pragma unroll
            for (int g = 0; g < 4; ++g)
#pragma unroll
                for (int ks = 0; ks < 4; ++ks)
                    afr[g][ks] = *(const short8*)(abase + (size_t)g * H_ * H_ + ks * 32);
        }
#pragma unroll
        for (int g = 0; g < 4; ++g)
#pragma unroll
            for (int ks = 0; ks < 4; ++ks)
                asm volatile("" : "+v"(afr[g][ks]));   // pin: defeat remat

        if (tid < 64) {
            int g = tid >> 4, qq = tid & 15;
            wxs[tid] = wx[(size_t)g * H_ + j0 + qq];
            bcs[tid] = biasc[(size_t)g * H_ + j0 + qq];
        }
#pragma unroll
        for (int i = tid; i < B_ * T_; i += 512)
            ys[(i >> 7) * 129 + (i & 127)] = y[i];
        cs[jlx * 33 + pb] = c0[(size_t)pb * H_ + j0 + jlx];
        __syncthreads();

        for (int t = 0; t < T_; ++t) {
            const u16* hp = (t == 0) ? h0 : (A + (size_t)(t - 1) * B_ * H_);

            if (t > 0) {
                // per-wave slice wait: 8 producers, each on its own 128B line
                const unsigned* fp = &flags[(kw * 8 + (lane & 7)) * 32];
                unsigned target = (unsigned)t;
                int guard = 0;
                for (;;) {
                    unsigned v = __hip_atomic_load(fp, __ATOMIC_RELAXED, __HIP_MEMORY_SCOPE_AGENT);
                    if (__all(v >= target)) break;
                    if (++guard > 20000000) break;
                }
                __atomic_signal_fence(__ATOMIC_ACQUIRE);
            }

            short8 bf0[4], bf1[4];
            {
                const u16* hb = hp + (size_t)jl * H_ + kw * 128 + kc;
#pragma unroll
                for (int ks = 0; ks < 4; ++ks) {
                    bf0[ks] = *(const short8*)(hb + ks * 32);
                    bf1[ks] = *(const short8*)(hb + (size_t)16 * H_ + ks * 32);
                }
            }
            f32x4 acc[4][2] = {};
#pragma unroll
            for (int ks = 0; ks < 4; ++ks) {
#pragma unroll
                for (int g = 0; g < 4; ++g) {
                    acc[g][0] = __builtin_amdgcn_mfma_f32_16x16x32_bf16(afr[g][ks], bf0[ks], acc[g][0], 0, 0, 0);
                    acc[g][1] = __builtin_amdgcn_mfma_f32_16x16x32_bf16(afr[g][ks], bf1[ks], acc[g][1], 0, 0, 0);
                }
            }
            int r0 = (lane >> 4) * 4;
#pragma unroll
            for (int g = 0; g < 4; ++g)
#pragma unroll
                for (int bt = 0; bt < 2; ++bt)
#pragma unroll
                    for (int r = 0; r < 4; ++r)
                        red[kw * 2112 + (g * 16 + r0 + r) * 33 + bt * 16 + jl] = acc[g][bt][r];
            __syncthreads();   // red RAW

            // ---- pointwise: every thread does ONE (jlx, pb) ----
            {
                float yv = ys[pb * 129 + t];
                float pg[4];
#pragma unroll
                for (int g = 0; g < 4; ++g) {
                    int row = (g * 16 + jlx) * 33 + pb;
                    float sum = red[row];
#pragma unroll
                    for (int ww = 1; ww < 8; ++ww) sum += red[ww * 2112 + row];
                    pg[g] = sum + wxs[g * 16 + jlx] * yv + bcs[g * 16 + jlx];
                }
                float iv = sigmf(pg[0]);
                float fv = sigmf(pg[1]);
                float gv = tanh_f(pg[2]);
                float ov = sigmf(pg[3]);
                float cv = fv * cs[jlx * 33 + pb] + iv * gv;
                cs[jlx * 33 + pb] = cv;
                float hv = ov * tanh_f(cv);

                unsigned h16 = (unsigned)f2bf(hv);
                unsigned oth = (unsigned)__shfl((int)h16, lane + 1, 64);  // jlx+1 partner
                if (!(jlx & 1)) {
                    uint32_t pk = h16 | (oth << 16);
                    __hip_atomic_store((uint32_t*)(A + ((size_t)t * B_ + pb) * H_ + j0 + jlx),
                                       pk, __ATOMIC_RELAXED, __HIP_MEMORY_SCOPE_AGENT);
                }
            }
            // Barrier drains every thread's vmcnt -> h_t stores visible.
            __syncthreads();
            if (tid == 0)
                __hip_atomic_store(&flags[bid * 32], (unsigned)(t + 1),
                                   __ATOMIC_RELAXED, __HIP_MEMORY_SCOPE_AGENT);
        }
        return;
    }

    // ================= gated output GEMM ==================================
    int orig = blockIdx.x - NBLK_REC;         // 0..1999
    int tb = orig / 500;                      // gate group, dispatch-ascending
    int wp = orig - tb * 500;
    int xcd = wp & 7, rest = wp >> 3;         // bijective swizzle: 500 = 8*62+4
    int wg = (xcd < 4 ? xcd * 63 : 252 + (xcd - 4) * 62) + rest;
    int bb = wg / 125;                        // 0..3
    int nb = wg - bb * 125;                   // 0..124
    int n0g = nb << 8;

    int wid = tid >> 6;
    int wm = wid >> 2, wn = wid & 3;
    int jl = lane & 15, kq = lane >> 4;

    // ---- converter duty: orig 0..127 convert 250 Wout rows each ----
    if (orig < 128) {
        const int QP = 250 * H_ / 4;          // 64000 quads per block
        long long qbase = (long long)orig * QP;
        for (int i = tid; i < QP; i += 512) {
            long long q = qbase + i;
            f32x4 v = *(const f32x4*)(Wout + q * 4);
            unsigned long long pk =
                (unsigned long long)((uint32_t)f2bf(v[0]) | ((uint32_t)f2bf(v[1]) << 16)) |
                ((unsigned long long)((uint32_t)f2bf(v[2]) | ((uint32_t)f2bf(v[3]) << 16)) << 32);
            __hip_atomic_store((unsigned long long*)Wo + q, pk,
                               __ATOMIC_RELAXED, __HIP_MEMORY_SCOPE_AGENT);
        }
        asm volatile("s_waitcnt vmcnt(0)" ::: "memory");
        __syncthreads();
        if (tid == 0)
            __hip_atomic_fetch_add(&flags[2048 + (orig & 63) * 32], 1u,
                                   __ATOMIC_RELAXED, __HIP_MEMORY_SCOPE_AGENT);
    }

    // ---- conv gate: Wo fully converted (64 lines, target 2 each) ----
    if (wid == 0) {
        const unsigned* fp = &flags[2048 + lane * 32];
        int guard = 0;
        for (;;) {
            unsigned v = __hip_atomic_load(fp, __ATOMIC_RELAXED, __HIP_MEMORY_SCOPE_AGENT);
            if (__all(v >= 2u)) break;
            __builtin_amdgcn_s_sleep(16);
            if (++guard > 20000000) break;   // hang-safety
        }
        __atomic_signal_fence(__ATOMIC_ACQUIRE);
    }
    __builtin_amdgcn_s_barrier();

    f32x4 acc[8][4] = {};

    // stage half-tile h (0=A0,1=A1,2=B0,3=B1) of K-tile `tile`
    auto stage = [&](int tile, int h) {
        u16* dst = sb + ((tile & 1) << 15) + (h << 13) + tid * 8;
#pragma unroll
        for (int ld = 0; ld < 2; ++ld) {
            int p = tid + (ld << 9);
            int row = p >> 3;
            int c16 = (p & 7) ^ (row & 7);        // inverse-swizzled source
            const u16* src;
            if (h < 2)
                src = A + ((size_t)(tb * 32 + (row & 31)) * B_
                           + (size_t)(bb * 8 + h * 4 + (row >> 5))) * H_
                        + tile * 64 + c16 * 8;
            else
                src = Wo + (size_t)(n0g + ((h - 2) << 7) + row) * H_
                         + tile * 64 + c16 * 8;
            gload16(src, dst + (ld << 12));
        }
    };

    // warm the B panels of tile 0 (Wo just converted)
    stage(0, 2); stage(0, 3);

    // ---- gate: wave 0 polls all 64 producer block-flag lines; others park --
    if (wid == 0) {
        unsigned target = (unsigned)((tb + 1) * 32);
        const unsigned* fp = &flags[lane * 32];
        int guard = 0;
        for (;;) {
            unsigned v = __hip_atomic_load(fp, __ATOMIC_RELAXED, __HIP_MEMORY_SCOPE_AGENT);
            if (__all(v >= target)) break;
            __builtin_amdgcn_s_sleep(32);
            if (++guard > 20000000) break;   // hang-safety
        }
        __atomic_signal_fence(__ATOMIC_ACQUIRE);
    }
    __builtin_amdgcn_s_barrier();

    // ---- prologue: A of tile0 + A0,B0 of tile1; leave 4 in flight ----
    stage(0, 0); stage(0, 1); stage(1, 0); stage(1, 2);
    asm volatile("s_waitcnt vmcnt(4)" ::: "memory");
    __builtin_amdgcn_s_barrier();

    const int NT = 16;   // K/64
    for (int tile = 0; tile < NT; ++tile) {
        const u16* buf = sb + ((tile & 1) << 15);
#pragma unroll
        for (int q = 0; q < 4; ++q) {
            const int mh = q >> 1, nh = q & 1;
            short8 af[4][2], bfr[2][2];
            const u16* bufA = buf + (mh << 13);
            const u16* bufB = buf + (1 << 14) + (nh << 13);
#pragma unroll
            for (int i = 0; i < 4; ++i) {
                int row = wm * 64 + (i << 4) + jl;
                int rx = (row & 7) << 3;
#pragma unroll
                for (int k2 = 0; k2 < 2; ++k2)
                    af[i][k2] = *(const short8*)(bufA + row * 64 + (((k2 << 5) + (kq << 3)) ^ rx));
            }
#pragma unroll
            for (int i = 0; i < 2; ++i) {
                int row = wn * 32 + (i << 4) + jl;
                int rx = (row & 7) << 3;
#pragma unroll
                for (int k2 = 0; k2 < 2; ++k2)
                    bfr[i][k2] = *(const short8*)(bufB + row * 64 + (((k2 << 5) + (kq << 3)) ^ rx));
            }
            if (q == 0) { if (tile + 1 < NT) stage(tile + 1, 1); }
            if (q == 1) { if (tile + 1 < NT) stage(tile + 1, 3); }
            if (q == 2) { if (tile + 2 < NT) stage(tile + 2, 0); }
            if (q == 3) { if (tile + 2 < NT) stage(tile + 2, 2); }

            asm volatile("" ::: "memory");
            __builtin_amdgcn_s_barrier();
            asm volatile("" ::: "memory");
            __builtin_amdgcn_s_setprio(1);
#pragma unroll
            for (int i = 0; i < 4; ++i)
#pragma unroll
                for (int jn = 0; jn < 2; ++jn)
#pragma unroll
                    for (int k2 = 0; k2 < 2; ++k2)
                        acc[mh * 4 + i][nh * 2 + jn] =
                            __builtin_amdgcn_mfma_f32_16x16x32_bf16(
                                af[i][k2], bfr[jn][k2], acc[mh * 4 + i][nh * 2 + jn], 0, 0, 0);
            __builtin_amdgcn_s_setprio(0);
            if (q == 3) {
                if (tile < 14) asm volatile("s_waitcnt vmcnt(4)" ::: "memory");
                else           asm volatile("s_waitcnt vmcnt(0)" ::: "memory");
            }
            asm volatile("" ::: "memory");
            __builtin_amdgcn_s_barrier();
        }
    }

    // ---- epilogue: fragment = one b x 16 consecutive t -> direct stores ----
#pragma unroll
    for (int nt = 0; nt < 4; ++nt) {
        int n = n0g + ((nt >> 1) << 7) + wn * 32 + ((nt & 1) << 4) + jl;
        float bias = bout[n];
#pragma unroll
        for (int mt = 0; mt < 8; ++mt) {
            int mh = mt >> 2, i = mt & 3;
            int bo = bb * 8 + mh * 4 + wm * 2 + (i >> 1);
            f32x4 v = acc[mt][nt];
            v[0] += bias; v[1] += bias; v[2] += bias; v[3] += bias;
            float* dst = out + ((size_t)bo * V_ + n) * T_ + tb * 32 + ((i & 1) << 4) + (kq << 2);
            *(f32x4*)dst = v;
        }
    }
}

// ---------------------------------------------------------------------------
extern "C" void kernel_launch(void* const* d_in, const int* in_sizes, int n_in,
                              void* d_out, int out_size, void* d_ws, size_t ws_size,
                              hipStream_t stream) {
    const float* y    = (const float*)d_in[0];   // [B,T]
    const float* enc  = (const float*)d_in[1];   // [B,H]
    const float* Wh   = (const float*)d_in[2];   // [H,H]
    const float* Wcp  = (const float*)d_in[3];   // [H,H]
    const float* Wih  = (const float*)d_in[4];   // [4H,1+H]
    const float* Whh  = (const float*)d_in[5];   // [4H,H]
    const float* bih  = (const float*)d_in[6];   // [4H]
    const float* bhh  = (const float*)d_in[7];   // [4H]
    const float* Wout = (const float*)d_in[8];   // [V,H]
    const float* bout = (const float*)d_in[9];   // [V]

    uint8_t* ws = (uint8_t*)d_ws;
    u16*  Wcomb = (u16*)ws;                                   // 8,388,608 B
    u16*  Wo    = (u16*)(ws + 8388608);                       // 65,536,000 B
    float* wx    = (float*)(ws + 8388608 + 65536000);
    float* biasc = wx + 4096;
    u16*  h0    = (u16*)(biasc + 4096);
    float* c     = (float*)(h0 + 32 * 1024);
    u16*  A     = (u16*)(c + 32 * 1024);                      // [T][B][H] bf16
    unsigned* flags = (unsigned*)(A + (size_t)4096 * 1024);   // 4096*4 B (line-spread)

    prep_mid<<<16896, 256, 0, stream>>>(Wih, Whh, bih, bhh, enc, Wh, Wcp,
                                        Wcomb, wx, biasc, flags, h0, c);

    fused_all<<<NBLK_REC + 2000, 512, 0, stream>>>(
        Wcomb, wx, biasc, h0, c, y, A, flags, Wo, Wout, bout, (float*)d_out);
}

// Round 16
// 675.698 us; speedup vs baseline: 1.5418x; 1.0225x over previous
//
#include <hip/hip_runtime.h>
#include <hip/hip_bf16.h>
#include <stdint.h>

#define B_ 32
#define T_ 128
#define H_ 1024
#define V_ 32000
#define NBLK_REC 64

typedef unsigned short u16;
typedef __attribute__((ext_vector_type(8))) short short8;
typedef __attribute__((ext_vector_type(4))) float f32x4;

static __device__ __forceinline__ u16 f2bf(float f) {
    uint32_t u = __float_as_uint(f);
    uint32_t r = (u + 0x7FFFu + ((u >> 16) & 1u)) >> 16;
    return (u16)r;
}

static __device__ __forceinline__ float sigmf(float x) {
    return 1.0f / (1.0f + __expf(-x));
}

static __device__ __forceinline__ float tanh_f(float x) {
    x = fminf(fmaxf(x, -20.f), 20.f);
    float e = __expf(2.f * x);
    return (e - 1.f) / (e + 1.f);
}

// Direct global->LDS 16B copy (dest is wave-uniform base + lane*16 in HW).
static __device__ __forceinline__ void gload16(const void* g, void* l) {
    __builtin_amdgcn_global_load_lds(
        (const __attribute__((address_space(1))) uint32_t*)g,
        (__attribute__((address_space(3))) uint32_t*)(uint32_t)(uintptr_t)l,
        16, 0, 0);
}

// ---------------------------------------------------------------------------
// Serial prep (small): W_comb conversion + wx/biasc + flag zero + h0/c0 init.
// Wout conversion lives in the fused kernel's gemm blocks (dead gate window).
// ---------------------------------------------------------------------------
__global__ void prep_mid(const float* __restrict__ Wih, const float* __restrict__ Whh,
                         const float* __restrict__ bih, const float* __restrict__ bhh,
                         const float* __restrict__ enc, const float* __restrict__ Wh,
                         const float* __restrict__ Wcp,
                         u16* __restrict__ Wc, float* __restrict__ wx,
                         float* __restrict__ biasc, unsigned* __restrict__ flags,
                         u16* __restrict__ h0, float* __restrict__ c0) {
    int blk = blockIdx.x;
    int tid = threadIdx.x;

    if (blk < 16384) {
        int idx = blk * 256 + tid;                 // 4096*1024 threads
        int r = idx >> 10, k = idx & 1023;
        float v = Wih[r * (H_ + 1) + 1 + k] + Whh[idx];
        Wc[idx] = f2bf(v);
        if (k == 0) {
            wx[r] = Wih[r * (H_ + 1)];
            biasc[r] = bih[r] + bhh[r];
        }
        if (idx < 4096) flags[idx] = 0u;           // re-zero every replay
        return;
    }
    {
        int gwid = (blk - 16384) * 4 + (tid >> 6);   // 2048 waves
        int lane = tid & 63;
        int sel = gwid >> 10;                // 0: h, 1: c
        int j = gwid & 1023;
        const float* W = sel ? Wcp : Wh;
        const float* wrow = W + (size_t)j * H_;
        f32x4 wv[4];
#pragma unroll
        for (int it = 0; it < 4; ++it)
            wv[it] = *(const f32x4*)(wrow + it * 256 + lane * 4);
#pragma unroll 2
        for (int b = 0; b < B_; ++b) {
            const float* erow = enc + (size_t)b * H_;
            float acc = 0.f;
#pragma unroll
            for (int it = 0; it < 4; ++it) {
                f32x4 ev = *(const f32x4*)(erow + it * 256 + lane * 4);
                acc += wv[it][0] * ev[0] + wv[it][1] * ev[1] + wv[it][2] * ev[2] + wv[it][3] * ev[3];
            }
#pragma unroll
            for (int s = 32; s >= 1; s >>= 1) acc += __shfl_xor(acc, s, 64);
            if (lane == 0) {
                if (sel) c0[(size_t)b * H_ + j] = acc;
                else     h0[(size_t)b * H_ + j] = f2bf(acc);
            }
        }
    }
}

// ---------------------------------------------------------------------------
// FUSED kernel: blocks 0..63 = persistent LSTM recurrence (r12/r15 protocol,
// proven); blocks 64..2063 = gated output GEMM — NOW 8 gate groups of 250
// blocks, m-tile = 16t x 16b (r11 geometry, ref-checked), halving the tail.
// Gemm blocks orig 0..127 first convert Wout fp32 -> Wo bf16 (250 rows each,
// agent stores), signalled on 64 spread lines (target 2 each).
// ---------------------------------------------------------------------------
__global__ __launch_bounds__(512, 2) void fused_all(
    const u16* __restrict__ Wc, const float* __restrict__ wx,
    const float* __restrict__ biasc, const u16* __restrict__ h0,
    const float* __restrict__ c0, const float* __restrict__ y,
    u16* __restrict__ A, unsigned* __restrict__ flags,
    u16* __restrict__ Wo, const float* __restrict__ Wout,
    const float* __restrict__ bout, float* __restrict__ out) {
    __shared__ __align__(16) u16 sb[65536];   // 128KB pool (both roles)

    int tid = threadIdx.x;
    int lane = tid & 63;

    if (blockIdx.x < NBLK_REC) {
        // ================= recurrence (r15 verbatim) ======================
        __builtin_amdgcn_s_setprio(2);       // latency-critical: outrank gemm
        float* red = (float*)sb;             // [8][64*33] = 16896 f
        float* cs  = red + 8 * 2112;         // [16][33]
        float* wxs = cs + 16 * 33;           // [64]
        float* bcs = wxs + 64;               // [64]
        float* ys  = bcs + 64;               // [32][129]

        int kw = tid >> 6;                   // wave id = K-slice
        int bid = blockIdx.x;
        int j0 = bid * 16;
        int jl = lane & 15;
        int kc = (lane >> 4) * 8;
        int jlx = tid & 15, pb = tid >> 4;   // pointwise: 1 (j,b) per thread

        short8 afr[4][4];
        {
            const u16* abase = Wc + (size_t)(j0 + jl) * H_ + kw * 128 + kc;
#pragma unroll
            for (int g = 0; g < 4; ++g)
#pragma unroll
                for (int ks = 0; ks < 4; ++ks)
                    afr[g][ks] = *(const short8*)(abase + (size_t)g * H_ * H_ + ks * 32);
        }
#pragma unroll
        for (int g = 0; g < 4; ++g)
#pragma unroll
            for (int ks = 0; ks < 4; ++ks)
                asm volatile("" : "+v"(afr[g][ks]));   // pin: defeat remat

        if (tid < 64) {
            int g = tid >> 4, qq = tid & 15;
            wxs[tid] = wx[(size_t)g * H_ + j0 + qq];
            bcs[tid] = biasc[(size_t)g * H_ + j0 + qq];
        }
#pragma unroll
        for (int i = tid; i < B_ * T_; i += 512)
            ys[(i >> 7) * 129 + (i & 127)] = y[i];
        cs[jlx * 33 + pb] = c0[(size_t)pb * H_ + j0 + jlx];
        __syncthreads();

        for (int t = 0; t < T_; ++t) {
            const u16* hp = (t == 0) ? h0 : (A + (size_t)(t - 1) * B_ * H_);

            if (t > 0) {
                // per-wave slice wait: 8 producers, each on its own 128B line
                const unsigned* fp = &flags[(kw * 8 + (lane & 7)) * 32];
                unsigned target = (unsigned)t;
                int guard = 0;
                for (;;) {
                    unsigned v = __hip_atomic_load(fp, __ATOMIC_RELAXED, __HIP_MEMORY_SCOPE_AGENT);
                    if (__all(v >= target)) break;
                    if (++guard > 20000000) break;
                }
                __atomic_signal_fence(__ATOMIC_ACQUIRE);
            }

            short8 bf0[4], bf1[4];
            {
                const u16* hb = hp + (size_t)jl * H_ + kw * 128 + kc;
#pragma unroll
                for (int ks = 0; ks < 4; ++ks) {
                    bf0[ks] = *(const short8*)(hb + ks * 32);
                    bf1[ks] = *(const short8*)(hb + (size_t)16 * H_ + ks * 32);
                }
            }
            f32x4 acc[4][2] = {};
#pragma unroll
            for (int ks = 0; ks < 4; ++ks) {
#pragma unroll
                for (int g = 0; g < 4; ++g) {
                    acc[g][0] = __builtin_amdgcn_mfma_f32_16x16x32_bf16(afr[g][ks], bf0[ks], acc[g][0], 0, 0, 0);
                    acc[g][1] = __builtin_amdgcn_mfma_f32_16x16x32_bf16(afr[g][ks], bf1[ks], acc[g][1], 0, 0, 0);
                }
            }
            int r0 = (lane >> 4) * 4;
#pragma unroll
            for (int g = 0; g < 4; ++g)
#pragma unroll
                for (int bt = 0; bt < 2; ++bt)
#pragma unroll
                    for (int r = 0; r < 4; ++r)
                        red[kw * 2112 + (g * 16 + r0 + r) * 33 + bt * 16 + jl] = acc[g][bt][r];
            __syncthreads();   // red RAW

            // ---- pointwise: every thread does ONE (jlx, pb) ----
            {
                float yv = ys[pb * 129 + t];
                float pg[4];
#pragma unroll
                for (int g = 0; g < 4; ++g) {
                    int row = (g * 16 + jlx) * 33 + pb;
                    float sum = red[row];
#pragma unroll
                    for (int ww = 1; ww < 8; ++ww) sum += red[ww * 2112 + row];
                    pg[g] = sum + wxs[g * 16 + jlx] * yv + bcs[g * 16 + jlx];
                }
                float iv = sigmf(pg[0]);
                float fv = sigmf(pg[1]);
                float gv = tanh_f(pg[2]);
                float ov = sigmf(pg[3]);
                float cv = fv * cs[jlx * 33 + pb] + iv * gv;
                cs[jlx * 33 + pb] = cv;
                float hv = ov * tanh_f(cv);

                unsigned h16 = (unsigned)f2bf(hv);
                unsigned oth = (unsigned)__shfl((int)h16, lane + 1, 64);  // jlx+1 partner
                if (!(jlx & 1)) {
                    uint32_t pk = h16 | (oth << 16);
                    __hip_atomic_store((uint32_t*)(A + ((size_t)t * B_ + pb) * H_ + j0 + jlx),
                                       pk, __ATOMIC_RELAXED, __HIP_MEMORY_SCOPE_AGENT);
                }
            }
            // Barrier drains every thread's vmcnt -> h_t stores visible.
            __syncthreads();
            if (tid == 0)
                __hip_atomic_store(&flags[bid * 32], (unsigned)(t + 1),
                                   __ATOMIC_RELAXED, __HIP_MEMORY_SCOPE_AGENT);
        }
        return;
    }

    // ================= gated output GEMM ==================================
    // m-tile = 16 t x 16 b: global m-row R: b = bb*16 + (R>>4), t = tb*16 + (R&15).
    // 8 gate groups of 250 blocks (tb = 0..7), gate target (tb+1)*16.
    int orig = blockIdx.x - NBLK_REC;         // 0..1999
    int tb = orig / 250;                      // gate group, dispatch-ascending
    int wp = orig - tb * 250;
    int xcd = wp & 7, rest = wp >> 3;         // bijective swizzle: 250 = 8*31+2
    int wg = (xcd < 2 ? xcd * 32 : 64 + (xcd - 2) * 31) + rest;
    int bb = wg / 125;                        // 0..1
    int nb = wg - bb * 125;                   // 0..124
    int n0g = nb << 8;

    int wid = tid >> 6;
    int wm = wid >> 2, wn = wid & 3;
    int jl = lane & 15, kq = lane >> 4;

    // ---- converter duty: orig 0..127 convert 250 Wout rows each ----
    if (orig < 128) {
        const int QP = 250 * H_ / 4;          // 64000 quads per block
        long long qbase = (long long)orig * QP;
        for (int i = tid; i < QP; i += 512) {
            long long q = qbase + i;
            f32x4 v = *(const f32x4*)(Wout + q * 4);
            unsigned long long pk =
                (unsigned long long)((uint32_t)f2bf(v[0]) | ((uint32_t)f2bf(v[1]) << 16)) |
                ((unsigned long long)((uint32_t)f2bf(v[2]) | ((uint32_t)f2bf(v[3]) << 16)) << 32);
            __hip_atomic_store((unsigned long long*)Wo + q, pk,
                               __ATOMIC_RELAXED, __HIP_MEMORY_SCOPE_AGENT);
        }
        asm volatile("s_waitcnt vmcnt(0)" ::: "memory");
        __syncthreads();
        if (tid == 0)
            __hip_atomic_fetch_add(&flags[2048 + (orig & 63) * 32], 1u,
                                   __ATOMIC_RELAXED, __HIP_MEMORY_SCOPE_AGENT);
    }

    // ---- conv gate: Wo fully converted (64 lines, target 2 each) ----
    if (wid == 0) {
        const unsigned* fp = &flags[2048 + lane * 32];
        int guard = 0;
        for (;;) {
            unsigned v = __hip_atomic_load(fp, __ATOMIC_RELAXED, __HIP_MEMORY_SCOPE_AGENT);
            if (__all(v >= 2u)) break;
            __builtin_amdgcn_s_sleep(16);
            if (++guard > 20000000) break;   // hang-safety
        }
        __atomic_signal_fence(__ATOMIC_ACQUIRE);
    }
    __builtin_amdgcn_s_barrier();

    f32x4 acc[8][4] = {};

    // stage half-tile h (0=A0,1=A1,2=B0,3=B1) of K-tile `tile`
    auto stage = [&](int tile, int h) {
        u16* dst = sb + ((tile & 1) << 15) + (h << 13) + tid * 8;
#pragma unroll
        for (int ld = 0; ld < 2; ++ld) {
            int p = tid + (ld << 9);
            int row = p >> 3;
            int c16 = (p & 7) ^ (row & 7);        // inverse-swizzled source
            const u16* src;
            if (h < 2)
                src = A + ((size_t)(tb * 16 + (row & 15)) * B_
                           + (size_t)(bb * 16 + h * 8 + (row >> 4))) * H_
                        + tile * 64 + c16 * 8;
            else
                src = Wo + (size_t)(n0g + ((h - 2) << 7) + row) * H_
                         + tile * 64 + c16 * 8;
            gload16(src, dst + (ld << 12));
        }
    };

    // warm the B panels of tile 0 (Wo just converted)
    stage(0, 2); stage(0, 3);

    // ---- gate: wave 0 polls all 64 producer block-flag lines; others park --
    if (wid == 0) {
        unsigned target = (unsigned)((tb + 1) * 16);
        const unsigned* fp = &flags[lane * 32];
        int guard = 0;
        for (;;) {
            unsigned v = __hip_atomic_load(fp, __ATOMIC_RELAXED, __HIP_MEMORY_SCOPE_AGENT);
            if (__all(v >= target)) break;
            __builtin_amdgcn_s_sleep(32);
            if (++guard > 20000000) break;   // hang-safety
        }
        __atomic_signal_fence(__ATOMIC_ACQUIRE);
    }
    __builtin_amdgcn_s_barrier();

    // ---- prologue: A of tile0 + A0,B0 of tile1; leave 4 in flight ----
    stage(0, 0); stage(0, 1); stage(1, 0); stage(1, 2);
    asm volatile("s_waitcnt vmcnt(4)" ::: "memory");
    __builtin_amdgcn_s_barrier();

    const int NT = 16;   // K/64
    for (int tile = 0; tile < NT; ++tile) {
        const u16* buf = sb + ((tile & 1) << 15);
#pragma unroll
        for (int q = 0; q < 4; ++q) {
            const int mh = q >> 1, nh = q & 1;
            short8 af[4][2], bfr[2][2];
            const u16* bufA = buf + (mh << 13);
            const u16* bufB = buf + (1 << 14) + (nh << 13);
#pragma unroll
            for (int i = 0; i < 4; ++i) {
                int row = wm * 64 + (i << 4) + jl;
                int rx = (row & 7) << 3;
#pragma unroll
                for (int k2 = 0; k2 < 2; ++k2)
                    af[i][k2] = *(const short8*)(bufA + row * 64 + (((k2 << 5) + (kq << 3)) ^ rx));
            }
#pragma unroll
            for (int i = 0; i < 2; ++i) {
                int row = wn * 32 + (i << 4) + jl;
                int rx = (row & 7) << 3;
#pragma unroll
                for (int k2 = 0; k2 < 2; ++k2)
                    bfr[i][k2] = *(const short8*)(bufB + row * 64 + (((k2 << 5) + (kq << 3)) ^ rx));
            }
            if (q == 0) { if (tile + 1 < NT) stage(tile + 1, 1); }
            if (q == 1) { if (tile + 1 < NT) stage(tile + 1, 3); }
            if (q == 2) { if (tile + 2 < NT) stage(tile + 2, 0); }
            if (q == 3) { if (tile + 2 < NT) stage(tile + 2, 2); }

            asm volatile("" ::: "memory");
            __builtin_amdgcn_s_barrier();
            asm volatile("" ::: "memory");
            __builtin_amdgcn_s_setprio(1);
#pragma unroll
            for (int i = 0; i < 4; ++i)
#pragma unroll
                for (int jn = 0; jn < 2; ++jn)
#pragma unroll
                    for (int k2 = 0; k2 < 2; ++k2)
                        acc[mh * 4 + i][nh * 2 + jn] =
                            __builtin_amdgcn_mfma_f32_16x16x32_bf16(
                                af[i][k2], bfr[jn][k2], acc[mh * 4 + i][nh * 2 + jn], 0, 0, 0);
            __builtin_amdgcn_s_setprio(0);
            if (q == 3) {
                if (tile < 14) asm volatile("s_waitcnt vmcnt(4)" ::: "memory");
                else           asm volatile("s_waitcnt vmcnt(0)" ::: "memory");
            }
            asm volatile("" ::: "memory");
            __builtin_amdgcn_s_barrier();
        }
    }

    // ---- epilogue: fragment = one b x 16 consecutive t -> direct stores ----
#pragma unroll
    for (int nt = 0; nt < 4; ++nt) {
        int n = n0g + ((nt >> 1) << 7) + wn * 32 + ((nt & 1) << 4) + jl;
        float bias = bout[n];
#pragma unroll
        for (int mt = 0; mt < 8; ++mt) {
            int bo = bb * 16 + ((mt >> 2) << 3) + wm * 4 + (mt & 3);
            f32x4 v = acc[mt][nt];
            v[0] += bias; v[1] += bias; v[2] += bias; v[3] += bias;
            float* dst = out + ((size_t)bo * V_ + n) * T_ + tb * 16 + (kq << 2);
            *(f32x4*)dst = v;
        }
    }
}

// ---------------------------------------------------------------------------
extern "C" void kernel_launch(void* const* d_in, const int* in_sizes, int n_in,
                              void* d_out, int out_size, void* d_ws, size_t ws_size,
                              hipStream_t stream) {
    const float* y    = (const float*)d_in[0];   // [B,T]
    const float* enc  = (const float*)d_in[1];   // [B,H]
    const float* Wh   = (const float*)d_in[2];   // [H,H]
    const float* Wcp  = (const float*)d_in[3];   // [H,H]
    const float* Wih  = (const float*)d_in[4];   // [4H,1+H]
    const float* Whh  = (const float*)d_in[5];   // [4H,H]
    const float* bih  = (const float*)d_in[6];   // [4H]
    const float* bhh  = (const float*)d_in[7];   // [4H]
    const float* Wout = (const float*)d_in[8];   // [V,H]
    const float* bout = (const float*)d_in[9];   // [V]

    uint8_t* ws = (uint8_t*)d_ws;
    u16*  Wcomb = (u16*)ws;                                   // 8,388,608 B
    u16*  Wo    = (u16*)(ws + 8388608);                       // 65,536,000 B
    float* wx    = (float*)(ws + 8388608 + 65536000);
    float* biasc = wx + 4096;
    u16*  h0    = (u16*)(biasc + 4096);
    float* c     = (float*)(h0 + 32 * 1024);
    u16*  A     = (u16*)(c + 32 * 1024);                      // [T][B][H] bf16
    unsigned* flags = (unsigned*)(A + (size_t)4096 * 1024);   // 4096*4 B (line-spread)

    prep_mid<<<16896, 256, 0, stream>>>(Wih, Whh, bih, bhh, enc, Wh, Wcp,
                                        Wcomb, wx, biasc, flags, h0, c);

    fused_all<<<NBLK_REC + 2000, 512, 0, stream>>>(
        Wcomb, wx, biasc, h0, c, y, A, flags, Wo, Wout, bout, (float*)d_out);
}

// Round 17
// 655.015 us; speedup vs baseline: 1.5905x; 1.0316x over previous
//
#include <hip/hip_runtime.h>
#include <hip/hip_bf16.h>
#include <stdint.h>

#define B_ 32
#define T_ 128
#define H_ 1024
#define V_ 32000
#define NBLK_REC 64

typedef unsigned short u16;
typedef __attribute__((ext_vector_type(8))) short short8;
typedef __attribute__((ext_vector_type(4))) float f32x4;

static __device__ __forceinline__ u16 f2bf(float f) {
    uint32_t u = __float_as_uint(f);
    uint32_t r = (u + 0x7FFFu + ((u >> 16) & 1u)) >> 16;
    return (u16)r;
}

static __device__ __forceinline__ float sigmf(float x) {
    return 1.0f / (1.0f + __expf(-x));
}

static __device__ __forceinline__ float tanh_f(float x) {
    x = fminf(fmaxf(x, -20.f), 20.f);
    float e = __expf(2.f * x);
    return (e - 1.f) / (e + 1.f);
}

// Direct global->LDS 16B copy (dest is wave-uniform base + lane*16 in HW).
static __device__ __forceinline__ void gload16(const void* g, void* l) {
    __builtin_amdgcn_global_load_lds(
        (const __attribute__((address_space(1))) uint32_t*)g,
        (__attribute__((address_space(3))) uint32_t*)(uint32_t)(uintptr_t)l,
        16, 0, 0);
}

// ---------------------------------------------------------------------------
// Serial prep (small): W_comb conversion (vectorized x4) + wx/biasc +
// flag zero + h0/c0 init. Grid = 4096 + 512 = 4608 blocks.
// ---------------------------------------------------------------------------
__global__ void prep_mid(const float* __restrict__ Wih, const float* __restrict__ Whh,
                         const float* __restrict__ bih, const float* __restrict__ bhh,
                         const float* __restrict__ enc, const float* __restrict__ Wh,
                         const float* __restrict__ Wcp,
                         u16* __restrict__ Wc, float* __restrict__ wx,
                         float* __restrict__ biasc, unsigned* __restrict__ flags,
                         u16* __restrict__ h0, float* __restrict__ c0) {
    int blk = blockIdx.x;
    int tid = threadIdx.x;

    if (blk < 4096) {
        int idx4 = blk * 256 + tid;                // 1,048,576 threads x 4 elems
        int base = idx4 * 4;
        int r = base >> 10, k = base & 1023;
        f32x4 hh = *(const f32x4*)(Whh + (size_t)r * H_ + k);
        const float* pih = Wih + (size_t)r * (H_ + 1) + 1 + k;
        uint2 st;
        st.x = (uint32_t)f2bf(pih[0] + hh[0]) | ((uint32_t)f2bf(pih[1] + hh[1]) << 16);
        st.y = (uint32_t)f2bf(pih[2] + hh[2]) | ((uint32_t)f2bf(pih[3] + hh[3]) << 16);
        *(uint2*)(Wc + base) = st;
        if (k == 0) {
            wx[r] = Wih[(size_t)r * (H_ + 1)];
            biasc[r] = bih[r] + bhh[r];
        }
        if (idx4 < 4096) flags[idx4] = 0u;         // re-zero every replay
        return;
    }
    {
        int gwid = (blk - 4096) * 4 + (tid >> 6);    // 2048 waves
        int lane = tid & 63;
        int sel = gwid >> 10;                // 0: h, 1: c
        int j = gwid & 1023;
        const float* W = sel ? Wcp : Wh;
        const float* wrow = W + (size_t)j * H_;
        f32x4 wv[4];
#pragma unroll
        for (int it = 0; it < 4; ++it)
            wv[it] = *(const f32x4*)(wrow + it * 256 + lane * 4);
#pragma unroll 2
        for (int b = 0; b < B_; ++b) {
            const float* erow = enc + (size_t)b * H_;
            float acc = 0.f;
#pragma unroll
            for (int it = 0; it < 4; ++it) {
                f32x4 ev = *(const f32x4*)(erow + it * 256 + lane * 4);
                acc += wv[it][0] * ev[0] + wv[it][1] * ev[1] + wv[it][2] * ev[2] + wv[it][3] * ev[3];
            }
#pragma unroll
            for (int s = 32; s >= 1; s >>= 1) acc += __shfl_xor(acc, s, 64);
            if (lane == 0) {
                if (sel) c0[(size_t)b * H_ + j] = acc;
                else     h0[(size_t)b * H_ + j] = f2bf(acc);
            }
        }
    }
}

// ---------------------------------------------------------------------------
// FUSED kernel: blocks 0..63 = persistent LSTM recurrence with SPLIT-WAIT
// (wait first 4 producers -> issue first-half h loads -> wait last 4, polls
// overlapping the in-flight loads -> issue second half -> MFMA);
// blocks 64..2063 = gated output GEMM (8 gate groups of 250, 16t x 16b).
// Gemm blocks orig 0..127 first convert Wout fp32 -> Wo bf16.
// ---------------------------------------------------------------------------
__global__ __launch_bounds__(512, 2) void fused_all(
    const u16* __restrict__ Wc, const float* __restrict__ wx,
    const float* __restrict__ biasc, const u16* __restrict__ h0,
    const float* __restrict__ c0, const float* __restrict__ y,
    u16* __restrict__ A, unsigned* __restrict__ flags,
    u16* __restrict__ Wo, const float* __restrict__ Wout,
    const float* __restrict__ bout, float* __restrict__ out) {
    __shared__ __align__(16) u16 sb[65536];   // 128KB pool (both roles)

    int tid = threadIdx.x;
    int lane = tid & 63;

    if (blockIdx.x < NBLK_REC) {
        // ================= recurrence =====================================
        __builtin_amdgcn_s_setprio(2);       // latency-critical: outrank gemm
        float* red = (float*)sb;             // [8][64*33] = 16896 f
        float* cs  = red + 8 * 2112;         // [16][33]
        float* wxs = cs + 16 * 33;           // [64]
        float* bcs = wxs + 64;               // [64]
        float* ys  = bcs + 64;               // [32][129]

        int kw = tid >> 6;                   // wave id = K-slice
        int bid = blockIdx.x;
        int j0 = bid * 16;
        int jl = lane & 15;
        int kc = (lane >> 4) * 8;
        int jlx = tid & 15, pb = tid >> 4;   // pointwise: 1 (j,b) per thread

        short8 afr[4][4];
        {
            const u16* abase = Wc + (size_t)(j0 + jl) * H_ + kw * 128 + kc;
#pragma unroll
            for (int g = 0; g < 4; ++g)
#pragma unroll
                for (int ks = 0; ks < 4; ++ks)
                    afr[g][ks] = *(const short8*)(abase + (size_t)g * H_ * H_ + ks * 32);
        }
#pragma unroll
        for (int g = 0; g < 4; ++g)
#pragma unroll
            for (int ks = 0; ks < 4; ++ks)
                asm volatile("" : "+v"(afr[g][ks]));   // pin: defeat remat

        if (tid < 64) {
            int g = tid >> 4, qq = tid & 15;
            wxs[tid] = wx[(size_t)g * H_ + j0 + qq];
            bcs[tid] = biasc[(size_t)g * H_ + j0 + qq];
        }
#pragma unroll
        for (int i = tid; i < B_ * T_; i += 512)
            ys[(i >> 7) * 129 + (i & 127)] = y[i];
        cs[jlx * 33 + pb] = c0[(size_t)pb * H_ + j0 + jlx];
        __syncthreads();

        for (int t = 0; t < T_; ++t) {
            const u16* hp = (t == 0) ? h0 : (A + (size_t)(t - 1) * B_ * H_);
            const u16* hb = hp + (size_t)jl * H_ + kw * 128 + kc;
            short8 bf0[4], bf1[4];

            // ---- wait FIRST 4 producers of this k-slice ----
            if (t > 0) {
                const unsigned* fp = &flags[(kw * 8 + (lane & 3)) * 32];
                unsigned target = (unsigned)t;
                int guard = 0;
                for (;;) {
                    unsigned v = __hip_atomic_load(fp, __ATOMIC_RELAXED, __HIP_MEMORY_SCOPE_AGENT);
                    if (__all(v >= target)) break;
                    if (++guard > 20000000) break;
                }
                __atomic_signal_fence(__ATOMIC_ACQUIRE);
            }
            // issue first-half h loads (ks 0,1 = k in [kw*128, kw*128+64))
#pragma unroll
            for (int ks = 0; ks < 2; ++ks) {
                bf0[ks] = *(const short8*)(hb + ks * 32);
                bf1[ks] = *(const short8*)(hb + (size_t)16 * H_ + ks * 32);
            }
            // ---- wait LAST 4 producers (polls overlap in-flight loads) ----
            if (t > 0) {
                const unsigned* fp = &flags[(kw * 8 + 4 + (lane & 3)) * 32];
                unsigned target = (unsigned)t;
                int guard = 0;
                for (;;) {
                    unsigned v = __hip_atomic_load(fp, __ATOMIC_RELAXED, __HIP_MEMORY_SCOPE_AGENT);
                    if (__all(v >= target)) break;
                    if (++guard > 20000000) break;
                }
                __atomic_signal_fence(__ATOMIC_ACQUIRE);
            }
#pragma unroll
            for (int ks = 2; ks < 4; ++ks) {
                bf0[ks] = *(const short8*)(hb + ks * 32);
                bf1[ks] = *(const short8*)(hb + (size_t)16 * H_ + ks * 32);
            }

            f32x4 acc[4][2] = {};
#pragma unroll
            for (int ks = 0; ks < 4; ++ks) {
#pragma unroll
                for (int g = 0; g < 4; ++g) {
                    acc[g][0] = __builtin_amdgcn_mfma_f32_16x16x32_bf16(afr[g][ks], bf0[ks], acc[g][0], 0, 0, 0);
                    acc[g][1] = __builtin_amdgcn_mfma_f32_16x16x32_bf16(afr[g][ks], bf1[ks], acc[g][1], 0, 0, 0);
                }
            }
            int r0 = (lane >> 4) * 4;
#pragma unroll
            for (int g = 0; g < 4; ++g)
#pragma unroll
                for (int bt = 0; bt < 2; ++bt)
#pragma unroll
                    for (int r = 0; r < 4; ++r)
                        red[kw * 2112 + (g * 16 + r0 + r) * 33 + bt * 16 + jl] = acc[g][bt][r];
            __syncthreads();   // red RAW

            // ---- pointwise: every thread does ONE (jlx, pb) ----
            {
                float yv = ys[pb * 129 + t];
                float pg[4];
#pragma unroll
                for (int g = 0; g < 4; ++g) {
                    int row = (g * 16 + jlx) * 33 + pb;
                    float sum = red[row];
#pragma unroll
                    for (int ww = 1; ww < 8; ++ww) sum += red[ww * 2112 + row];
                    pg[g] = sum + wxs[g * 16 + jlx] * yv + bcs[g * 16 + jlx];
                }
                float iv = sigmf(pg[0]);
                float fv = sigmf(pg[1]);
                float gv = tanh_f(pg[2]);
                float ov = sigmf(pg[3]);
                float cv = fv * cs[jlx * 33 + pb] + iv * gv;
                cs[jlx * 33 + pb] = cv;
                float hv = ov * tanh_f(cv);

                unsigned h16 = (unsigned)f2bf(hv);
                unsigned oth = (unsigned)__shfl((int)h16, lane + 1, 64);  // jlx+1 partner
                if (!(jlx & 1)) {
                    uint32_t pk = h16 | (oth << 16);
                    __hip_atomic_store((uint32_t*)(A + ((size_t)t * B_ + pb) * H_ + j0 + jlx),
                                       pk, __ATOMIC_RELAXED, __HIP_MEMORY_SCOPE_AGENT);
                }
            }
            // Barrier drains every thread's vmcnt -> h_t stores visible.
            __syncthreads();
            if (tid == 0)
                __hip_atomic_store(&flags[bid * 32], (unsigned)(t + 1),
                                   __ATOMIC_RELAXED, __HIP_MEMORY_SCOPE_AGENT);
        }
        return;
    }

    // ================= gated output GEMM ==================================
    // m-tile = 16 t x 16 b: global m-row R: b = bb*16 + (R>>4), t = tb*16 + (R&15).
    // 8 gate groups of 250 blocks (tb = 0..7), gate target (tb+1)*16.
    int orig = blockIdx.x - NBLK_REC;         // 0..1999
    int tb = orig / 250;                      // gate group, dispatch-ascending
    int wp = orig - tb * 250;
    int xcd = wp & 7, rest = wp >> 3;         // bijective swizzle: 250 = 8*31+2
    int wg = (xcd < 2 ? xcd * 32 : 64 + (xcd - 2) * 31) + rest;
    int bb = wg / 125;                        // 0..1
    int nb = wg - bb * 125;                   // 0..124
    int n0g = nb << 8;

    int wid = tid >> 6;
    int wm = wid >> 2, wn = wid & 3;
    int jl = lane & 15, kq = lane >> 4;

    // ---- converter duty: orig 0..127 convert 250 Wout rows each ----
    if (orig < 128) {
        const int QP = 250 * H_ / 4;          // 64000 quads per block
        long long qbase = (long long)orig * QP;
        for (int i = tid; i < QP; i += 512) {
            long long q = qbase + i;
            f32x4 v = *(const f32x4*)(Wout + q * 4);
            unsigned long long pk =
                (unsigned long long)((uint32_t)f2bf(v[0]) | ((uint32_t)f2bf(v[1]) << 16)) |
                ((unsigned long long)((uint32_t)f2bf(v[2]) | ((uint32_t)f2bf(v[3]) << 16)) << 32);
            __hip_atomic_store((unsigned long long*)Wo + q, pk,
                               __ATOMIC_RELAXED, __HIP_MEMORY_SCOPE_AGENT);
        }
        asm volatile("s_waitcnt vmcnt(0)" ::: "memory");
        __syncthreads();
        if (tid == 0)
            __hip_atomic_fetch_add(&flags[2048 + (orig & 63) * 32], 1u,
                                   __ATOMIC_RELAXED, __HIP_MEMORY_SCOPE_AGENT);
    }

    // ---- conv gate: Wo fully converted (64 lines, target 2 each) ----
    if (wid == 0) {
        const unsigned* fp = &flags[2048 + lane * 32];
        int guard = 0;
        for (;;) {
            unsigned v = __hip_atomic_load(fp, __ATOMIC_RELAXED, __HIP_MEMORY_SCOPE_AGENT);
            if (__all(v >= 2u)) break;
            __builtin_amdgcn_s_sleep(16);
            if (++guard > 20000000) break;   // hang-safety
        }
        __atomic_signal_fence(__ATOMIC_ACQUIRE);
    }
    __builtin_amdgcn_s_barrier();

    f32x4 acc[8][4] = {};

    // stage half-tile h (0=A0,1=A1,2=B0,3=B1) of K-tile `tile`
    auto stage = [&](int tile, int h) {
        u16* dst = sb + ((tile & 1) << 15) + (h << 13) + tid * 8;
#pragma unroll
        for (int ld = 0; ld < 2; ++ld) {
            int p = tid + (ld << 9);
            int row = p >> 3;
            int c16 = (p & 7) ^ (row & 7);        // inverse-swizzled source
            const u16* src;
            if (h < 2)
                src = A + ((size_t)(tb * 16 + (row & 15)) * B_
                           + (size_t)(bb * 16 + h * 8 + (row >> 4))) * H_
                        + tile * 64 + c16 * 8;
            else
                src = Wo + (size_t)(n0g + ((h - 2) << 7) + row) * H_
                         + tile * 64 + c16 * 8;
            gload16(src, dst + (ld << 12));
        }
    };

    // warm the B panels of tile 0 (Wo just converted)
    stage(0, 2); stage(0, 3);

    // ---- gate: wave 0 polls all 64 producer block-flag lines; others park --
    if (wid == 0) {
        unsigned target = (unsigned)((tb + 1) * 16);
        const unsigned* fp = &flags[lane * 32];
        int guard = 0;
        for (;;) {
            unsigned v = __hip_atomic_load(fp, __ATOMIC_RELAXED, __HIP_MEMORY_SCOPE_AGENT);
            if (__all(v >= target)) break;
            __builtin_amdgcn_s_sleep(32);
            if (++guard > 20000000) break;   // hang-safety
        }
        __atomic_signal_fence(__ATOMIC_ACQUIRE);
    }
    __builtin_amdgcn_s_barrier();

    // ---- prologue: A of tile0 + A0,B0 of tile1; leave 4 in flight ----
    stage(0, 0); stage(0, 1); stage(1, 0); stage(1, 2);
    asm volatile("s_waitcnt vmcnt(4)" ::: "memory");
    __builtin_amdgcn_s_barrier();

    const int NT = 16;   // K/64
    for (int tile = 0; tile < NT; ++tile) {
        const u16* buf = sb + ((tile & 1) << 15);
#pragma unroll
        for (int q = 0; q < 4; ++q) {
            const int mh = q >> 1, nh = q & 1;
            short8 af[4][2], bfr[2][2];
            const u16* bufA = buf + (mh << 13);
            const u16* bufB = buf + (1 << 14) + (nh << 13);
#pragma unroll
            for (int i = 0; i < 4; ++i) {
                int row = wm * 64 + (i << 4) + jl;
                int rx = (row & 7) << 3;
#pragma unroll
                for (int k2 = 0; k2 < 2; ++k2)
                    af[i][k2] = *(const short8*)(bufA + row * 64 + (((k2 << 5) + (kq << 3)) ^ rx));
            }
#pragma unroll
            for (int i = 0; i < 2; ++i) {
                int row = wn * 32 + (i << 4) + jl;
                int rx = (row & 7) << 3;
#pragma unroll
                for (int k2 = 0; k2 < 2; ++k2)
                    bfr[i][k2] = *(const short8*)(bufB + row * 64 + (((k2 << 5) + (kq << 3)) ^ rx));
            }
            if (q == 0) { if (tile + 1 < NT) stage(tile + 1, 1); }
            if (q == 1) { if (tile + 1 < NT) stage(tile + 1, 3); }
            if (q == 2) { if (tile + 2 < NT) stage(tile + 2, 0); }
            if (q == 3) { if (tile + 2 < NT) stage(tile + 2, 2); }

            asm volatile("" ::: "memory");
            __builtin_amdgcn_s_barrier();
            asm volatile("" ::: "memory");
            __builtin_amdgcn_s_setprio(1);
#pragma unroll
            for (int i = 0; i < 4; ++i)
#pragma unroll
                for (int jn = 0; jn < 2; ++jn)
#pragma unroll
                    for (int k2 = 0; k2 < 2; ++k2)
                        acc[mh * 4 + i][nh * 2 + jn] =
                            __builtin_amdgcn_mfma_f32_16x16x32_bf16(
                                af[i][k2], bfr[jn][k2], acc[mh * 4 + i][nh * 2 + jn], 0, 0, 0);
            __builtin_amdgcn_s_setprio(0);
            if (q == 3) {
                if (tile < 14) asm volatile("s_waitcnt vmcnt(4)" ::: "memory");
                else           asm volatile("s_waitcnt vmcnt(0)" ::: "memory");
            }
            asm volatile("" ::: "memory");
            __builtin_amdgcn_s_barrier();
        }
    }

    // ---- epilogue: fragment = one b x 16 consecutive t -> direct stores ----
#pragma unroll
    for (int nt = 0; nt < 4; ++nt) {
        int n = n0g + ((nt >> 1) << 7) + wn * 32 + ((nt & 1) << 4) + jl;
        float bias = bout[n];
#pragma unroll
        for (int mt = 0; mt < 8; ++mt) {
            int bo = bb * 16 + ((mt >> 2) << 3) + wm * 4 + (mt & 3);
            f32x4 v = acc[mt][nt];
            v[0] += bias; v[1] += bias; v[2] += bias; v[3] += bias;
            float* dst = out + ((size_t)bo * V_ + n) * T_ + tb * 16 + (kq << 2);
            *(f32x4*)dst = v;
        }
    }
}

// ---------------------------------------------------------------------------
extern "C" void kernel_launch(void* const* d_in, const int* in_sizes, int n_in,
                              void* d_out, int out_size, void* d_ws, size_t ws_size,
                              hipStream_t stream) {
    const float* y    = (const float*)d_in[0];   // [B,T]
    const float* enc  = (const float*)d_in[1];   // [B,H]
    const float* Wh   = (const float*)d_in[2];   // [H,H]
    const float* Wcp  = (const float*)d_in[3];   // [H,H]
    const float* Wih  = (const float*)d_in[4];   // [4H,1+H]
    const float* Whh  = (const float*)d_in[5];   // [4H,H]
    const float* bih  = (const float*)d_in[6];   // [4H]
    const float* bhh  = (const float*)d_in[7];   // [4H]
    const float* Wout = (const float*)d_in[8];   // [V,H]
    const float* bout = (const float*)d_in[9];   // [V]

    uint8_t* ws = (uint8_t*)d_ws;
    u16*  Wcomb = (u16*)ws;                                   // 8,388,608 B
    u16*  Wo    = (u16*)(ws + 8388608);                       // 65,536,000 B
    float* wx    = (float*)(ws + 8388608 + 65536000);
    float* biasc = wx + 4096;
    u16*  h0    = (u16*)(biasc + 4096);
    float* c     = (float*)(h0 + 32 * 1024);
    u16*  A     = (u16*)(c + 32 * 1024);                      // [T][B][H] bf16
    unsigned* flags = (unsigned*)(A + (size_t)4096 * 1024);   // 4096*4 B (line-spread)

    prep_mid<<<4608, 256, 0, stream>>>(Wih, Whh, bih, bhh, enc, Wh, Wcp,
                                       Wcomb, wx, biasc, flags, h0, c);

    fused_all<<<NBLK_REC + 2000, 512, 0, stream>>>(
        Wcomb, wx, biasc, h0, c, y, A, flags, Wo, Wout, bout, (float*)d_out);
}